// Round 1
// baseline (485.930 us; speedup 1.0000x reference)
//
#include <hip/hip_runtime.h>
#include <math.h>

// Problem constants (B=2, H=8, L=2048, E=512, d=64)
constexpr int CB = 2, CH = 8, CL = 2048, CD = 64, CE = 512;
constexpr int NROW = CB * CH * CL;          // 32768 rows (b,h,s)
constexpr int XSTRIDE = 66;                 // 33 complex per row
constexpr float SCALE = 1.0f / 2048.0f;     // irfft 1/n
constexpr float TWO_PI = 6.283185307179586f;

// Workspace layout (floats). Total = 4,456,448 floats = 17.8 MB.
// X region is dead after k2 and reused for vt (= v/Z).
constexpr size_t OFF_COEF  = 0;                         // [NROW][64]
constexpr size_t OFF_C0S   = OFF_COEF + (size_t)NROW*64;// [NROW] (C0 - M)
constexpr size_t OFF_Z     = OFF_C0S + NROW;            // [NROW]
constexpr size_t OFF_BASIS = OFF_Z + NROW;              // [64][2048]
constexpr size_t OFF_X     = OFF_BASIS + (size_t)64*CL; // [NROW][66]  (union w/ vt)
constexpr size_t OFF_VT    = OFF_X;                     // [NROW][64]

// ---------------------------------------------------------------- k0: basis
// basis[j][t]    = cos(2*pi*(j+1)*t/2048), j=0..31
// basis[32+j][t] = sin(2*pi*(j+1)*t/2048)
__global__ void k0_basis(float* __restrict__ basis) {
  int t = blockIdx.x * 256 + threadIdx.x;
  if (t >= CL) return;
  for (int j = 0; j < 32; ++j) {
    int kk = ((j + 1) * t) & (CL - 1);      // exact reduction mod 2048
    float ang = (float)kk * (TWO_PI / (float)CL);
    float s, c;
    sincosf(ang, &s, &c);
    basis[j * CL + t] = c;
    basis[(32 + j) * CL + t] = s;
  }
}

// ---------------------------------------------------------------- k1: X_f
// Per row (b,h,s): 64-point DFT of q-row and k-row (33 bins), X = Q*conj(K).
__global__ void k1_dft(const float* __restrict__ q, const float* __restrict__ kin,
                       float* __restrict__ X) {
  __shared__ float qs[4][64], ks[4][64], twc[64], tws[64];
  int tid = threadIdx.x;
  if (tid < 64) {
    float ang = (float)tid * (TWO_PI / 64.0f);
    twc[tid] = cosf(ang);
    tws[tid] = sinf(ang);
  }
  int r = tid >> 6, lane = tid & 63;
  int row = blockIdx.x * 4 + r;
  int b = row >> 14, h = (row >> 11) & 7, s = row & 2047;
  size_t gofs = ((size_t)(b * CL + s)) * CE + h * 64 + lane;
  qs[r][lane] = q[gofs];
  ks[r][lane] = kin[gofs];
  __syncthreads();
  if (lane < 33) {
    float qr = 0, qi = 0, kr = 0, ki = 0;
    for (int c = 0; c < 64; ++c) {
      int idx = (lane * c) & 63;
      float cc = twc[idx], ss = tws[idx];
      float qv = qs[r][c], kv = ks[r][c];
      qr += qv * cc; qi -= qv * ss;     // e^{-i theta}
      kr += kv * cc; ki -= kv * ss;
    }
    float xre = qr * kr + qi * ki;      // Q * conj(K)
    float xim = qi * kr - qr * ki;
    X[(size_t)row * XSTRIDE + 2 * lane]     = xre;
    X[(size_t)row * XSTRIDE + 2 * lane + 1] = xim;
  }
}

// ---------------------------------------------------------------- k2: coefs
// Subtract head-mean of X per (b,s,f); emit per row:
//   coef[row][j]    = A_{j+1} = 2*ReY/2048   (cos coefs)
//   coef[row][32+j] = B_{j+1} = -2*ImY/2048  (sin coefs)
//   c0s[row]        = C0 - M,  M = |C0| + sum(|A|+|B|)  (>= max_t y)
// Also zero-inits Z (ws is poisoned each launch).
__global__ void k2_coef(const float* __restrict__ X, float* __restrict__ coef,
                        float* __restrict__ c0s, float* __restrict__ Z) {
  __shared__ float mre[33], mim[33], lm[8 * 33], c0v[8];
  int tid = threadIdx.x;
  int bs = blockIdx.x;                  // b*2048 + s
  int b = bs >> 11, s = bs & 2047;
  if (tid < 33) {
    float sr = 0, si = 0;
    for (int h = 0; h < 8; ++h) {
      size_t row = (size_t)((b * 8 + h) * 2048 + s);
      sr += X[row * XSTRIDE + 2 * tid];
      si += X[row * XSTRIDE + 2 * tid + 1];
    }
    mre[tid] = sr * 0.125f;
    mim[tid] = si * 0.125f;
  }
  __syncthreads();
  for (int p = tid; p < 264; p += 256) {
    int h = p / 33, f = p - h * 33;
    size_t row = (size_t)((b * 8 + h) * 2048 + s);
    float yre = X[row * XSTRIDE + 2 * f] - mre[f];
    float yim = X[row * XSTRIDE + 2 * f + 1] - mim[f];
    if (f == 0) {
      float c0 = yre * SCALE;
      c0v[h] = c0;
      lm[h * 33] = fabsf(c0);
    } else {
      float a  =  2.0f * yre * SCALE;
      float bb = -2.0f * yim * SCALE;
      coef[row * 64 + (f - 1)]      = a;
      coef[row * 64 + 32 + (f - 1)] = bb;
      lm[h * 33 + f] = fabsf(a) + fabsf(bb);
    }
  }
  __syncthreads();
  if (tid < 8) {
    float m = 0;
    for (int f = 0; f < 33; ++f) m += lm[tid * 33 + f];
    size_t row = (size_t)((b * 8 + tid) * 2048 + s);
    c0s[row] = c0v[tid] - m;
    Z[row] = 0.0f;
  }
}

// ---------------------------------------------------------------- k3: Z
// Tiled GEMM (64 rows x 128 cols, K=64) -> exp -> row-sum -> atomicAdd Z.
__launch_bounds__(256)
__global__ void k3_z(const float* __restrict__ coef, const float* __restrict__ c0s,
                     const float* __restrict__ basis, float* __restrict__ Z) {
  __shared__ float As[64 * 64];   // [k][row_local] (transposed stage)
  __shared__ float Bs[64 * 128];  // [k][col_local]
  __shared__ float ps[64 * 32];
  __shared__ float c0loc[64];
  int tid = threadIdx.x;
  int rowbase = blockIdx.x * 64;
  int cbase = blockIdx.y * 128;
  {
    int rr = tid >> 2, kq = (tid & 3) * 16;
    const float4* src = (const float4*)(coef + (size_t)(rowbase + rr) * 64 + kq);
#pragma unroll
    for (int m = 0; m < 4; ++m) {
      float4 vv = src[m];
      int k = kq + 4 * m;
      As[(k + 0) * 64 + rr] = vv.x;
      As[(k + 1) * 64 + rr] = vv.y;
      As[(k + 2) * 64 + rr] = vv.z;
      As[(k + 3) * 64 + rr] = vv.w;
    }
  }
  {
    int j = tid >> 2, cq = (tid & 3) * 32;
    const float4* src = (const float4*)(basis + (size_t)j * CL + cbase + cq);
    float4* dst = (float4*)(Bs + j * 128 + cq);
#pragma unroll
    for (int m = 0; m < 8; ++m) dst[m] = src[m];
  }
  if (tid < 64) c0loc[tid] = c0s[rowbase + tid];
  __syncthreads();
  int r0 = (tid >> 5) * 8;
  int c0l = (tid & 31) * 4;
  float y[8][4];
#pragma unroll
  for (int i = 0; i < 8; ++i) {
    float cv = c0loc[r0 + i];
    y[i][0] = cv; y[i][1] = cv; y[i][2] = cv; y[i][3] = cv;
  }
  for (int k = 0; k < 64; ++k) {
    float4 bv = *(const float4*)(Bs + k * 128 + c0l);
    float4 a0 = *(const float4*)(As + k * 64 + r0);
    float4 a1 = *(const float4*)(As + k * 64 + r0 + 4);
    float av[8] = {a0.x, a0.y, a0.z, a0.w, a1.x, a1.y, a1.z, a1.w};
#pragma unroll
    for (int i = 0; i < 8; ++i) {
      y[i][0] += av[i] * bv.x; y[i][1] += av[i] * bv.y;
      y[i][2] += av[i] * bv.z; y[i][3] += av[i] * bv.w;
    }
  }
#pragma unroll
  for (int i = 0; i < 8; ++i) {
    float e = __expf(y[i][0]) + __expf(y[i][1]) + __expf(y[i][2]) + __expf(y[i][3]);
    ps[(r0 + i) * 32 + (tid & 31)] = e;
  }
  __syncthreads();
  if (tid < 64) {
    float ssum = 0;
#pragma unroll
    for (int j = 0; j < 32; ++j) ssum += ps[tid * 32 + j];
    atomicAdd(&Z[rowbase + tid], ssum);
  }
}

// ---------------------------------------------------------------- k3b: vt
__global__ void k3b_vt(const float* __restrict__ values, const float* __restrict__ Z,
                       float* __restrict__ vt) {
  int idx = blockIdx.x * 256 + threadIdx.x;   // < NROW*64
  int row = idx >> 6, dd = idx & 63;
  int b = row >> 14, h = (row >> 11) & 7, s = row & 2047;
  vt[idx] = values[(size_t)(b * CL + s) * CE + h * 64 + dd] / Z[row];
}

// ---------------------------------------------------------------- k4: output
// Per (b,h) x 64-col tile: loop 64-s tiles: E = exp(logit tile) -> LDS,
// then Out[d, l] += vt^T[d, s] @ E[s, l]. Direct final stores (full coverage).
__launch_bounds__(256)
__global__ void k4_out(const float* __restrict__ coef, const float* __restrict__ c0s,
                       const float* __restrict__ basis, const float* __restrict__ vt,
                       float* __restrict__ out) {
  __shared__ float Bsm[64 * 64];
  __shared__ float As[64 * 64];
  __shared__ float Es[64 * 64];
  __shared__ float Vs[64 * 64];
  __shared__ float c0loc[64];
  int tid = threadIdx.x;
  int bh = blockIdx.x;     // 0..15
  int l0 = blockIdx.y * 64;
  int b = bh >> 3, h = bh & 7;
  {
    int j = tid >> 2, cq = (tid & 3) * 16;
    const float4* src = (const float4*)(basis + (size_t)j * CL + l0 + cq);
    float4* dst = (float4*)(Bsm + j * 64 + cq);
#pragma unroll
    for (int m = 0; m < 4; ++m) dst[m] = src[m];
  }
  int grp = tid >> 4;      // 0..15
  int cg = tid & 15;
  int sr0 = grp * 4;       // E-phase row group
  int d0 = grp * 4;        // PV-phase d group
  int cl = cg * 4;
  float acc[4][4];
#pragma unroll
  for (int i = 0; i < 4; ++i)
#pragma unroll
    for (int j = 0; j < 4; ++j) acc[i][j] = 0.0f;

  for (int st = 0; st < 32; ++st) {
    int rowbase = bh * CL + st * 64;
    __syncthreads();   // prev-iter LDS reads done before restaging
    {
      int rr = tid >> 2, kq = (tid & 3) * 16;
      const float4* src = (const float4*)(coef + (size_t)(rowbase + rr) * 64 + kq);
#pragma unroll
      for (int m = 0; m < 4; ++m) {
        float4 vv = src[m];
        int k = kq + 4 * m;
        As[(k + 0) * 64 + rr] = vv.x;
        As[(k + 1) * 64 + rr] = vv.y;
        As[(k + 2) * 64 + rr] = vv.z;
        As[(k + 3) * 64 + rr] = vv.w;
      }
    }
    {
      int ss = tid >> 2, dq = (tid & 3) * 16;
      const float4* src = (const float4*)(vt + (size_t)(rowbase + ss) * 64 + dq);
      float4* dst = (float4*)(Vs + ss * 64 + dq);
#pragma unroll
      for (int m = 0; m < 4; ++m) dst[m] = src[m];
    }
    if (tid < 64) c0loc[tid] = c0s[rowbase + tid];
    __syncthreads();
    // E phase: 4x4 logit sub-tile, K=64
    float y[4][4];
#pragma unroll
    for (int i = 0; i < 4; ++i) {
      float cv = c0loc[sr0 + i];
      y[i][0] = cv; y[i][1] = cv; y[i][2] = cv; y[i][3] = cv;
    }
    for (int k = 0; k < 64; ++k) {
      float4 bv = *(const float4*)(Bsm + k * 64 + cl);
      float4 av = *(const float4*)(As + k * 64 + sr0);
      float a[4] = {av.x, av.y, av.z, av.w};
#pragma unroll
      for (int i = 0; i < 4; ++i) {
        y[i][0] += a[i] * bv.x; y[i][1] += a[i] * bv.y;
        y[i][2] += a[i] * bv.z; y[i][3] += a[i] * bv.w;
      }
    }
#pragma unroll
    for (int i = 0; i < 4; ++i) {
      float4 e;
      e.x = __expf(y[i][0]); e.y = __expf(y[i][1]);
      e.z = __expf(y[i][2]); e.w = __expf(y[i][3]);
      *(float4*)(Es + (sr0 + i) * 64 + cl) = e;
    }
    __syncthreads();
    // PV phase: outer-product accumulate over the 64-s tile
    for (int s = 0; s < 64; ++s) {
      float4 vv = *(const float4*)(Vs + s * 64 + d0);
      float4 ee = *(const float4*)(Es + s * 64 + cl);
      float vr[4] = {vv.x, vv.y, vv.z, vv.w};
      float er[4] = {ee.x, ee.y, ee.z, ee.w};
#pragma unroll
      for (int i = 0; i < 4; ++i)
#pragma unroll
        for (int j = 0; j < 4; ++j)
          acc[i][j] += vr[i] * er[j];
    }
  }
  // out flat layout: [b][d][h][l]  (faithful to transpose(0,2,1,3).reshape)
#pragma unroll
  for (int i = 0; i < 4; ++i) {
    float4 o;
    o.x = acc[i][0]; o.y = acc[i][1]; o.z = acc[i][2]; o.w = acc[i][3];
    *(float4*)(out + (size_t)((b * 64 + d0 + i) * 8 + h) * 2048 + l0 + cl) = o;
  }
}

extern "C" void kernel_launch(void* const* d_in, const int* in_sizes, int n_in,
                              void* d_out, int out_size, void* d_ws, size_t ws_size,
                              hipStream_t stream) {
  const float* q = (const float*)d_in[0];
  const float* k = (const float*)d_in[1];
  const float* v = (const float*)d_in[2];
  float* out = (float*)d_out;
  float* ws = (float*)d_ws;          // needs >= 17.9 MB
  float* coef  = ws + OFF_COEF;
  float* c0s   = ws + OFF_C0S;
  float* Z     = ws + OFF_Z;
  float* basis = ws + OFF_BASIS;
  float* X     = ws + OFF_X;
  float* vt    = ws + OFF_VT;

  k0_basis<<<dim3(8), dim3(256), 0, stream>>>(basis);
  k1_dft<<<dim3(8192), dim3(256), 0, stream>>>(q, k, X);
  k2_coef<<<dim3(CB * CL), dim3(256), 0, stream>>>(X, coef, c0s, Z);
  k3_z<<<dim3(512, 16), dim3(256), 0, stream>>>(coef, c0s, basis, Z);
  k3b_vt<<<dim3(8192), dim3(256), 0, stream>>>(v, Z, vt);
  k4_out<<<dim3(16, 32), dim3(256), 0, stream>>>(coef, c0s, basis, vt, out);
}

// Round 2
// 421.139 us; speedup vs baseline: 1.1538x; 1.1538x over previous
//
#include <hip/hip_runtime.h>
#include <math.h>

// B=2, H=8, L=2048, E=512, d=64
constexpr int CL = 2048, CE = 512;
constexpr int NROW = 32768;                 // b*h*s rows
constexpr int XSTRIDE = 66;
constexpr float SCALE = 1.0f / 2048.0f;
constexpr float TWO_PI = 6.283185307179586f;

typedef short short8 __attribute__((ext_vector_type(8)));
typedef float floatx4 __attribute__((ext_vector_type(4)));

__device__ inline unsigned short f2bf(float f) {
  union { float f; unsigned u; } c; c.f = f;
  unsigned u = c.u + 0x7FFF + ((c.u >> 16) & 1);
  return (unsigned short)(u >> 16);
}
__device__ inline float bf2f(unsigned short h) {
  union { unsigned u; float f; } c; c.u = ((unsigned)h) << 16;
  return c.f;
}
__device__ inline float hi2f(unsigned u) {   // high 16 bits as bf16
  union { unsigned u; float f; } c; c.u = u & 0xFFFF0000u;
  return c.f;
}
__device__ inline float lo2f(unsigned u) {   // low 16 bits as bf16
  union { unsigned u; float f; } c; c.u = u << 16;
  return c.f;
}

// Workspace (17.8 MB):
//   float c0s[NROW]; float Z[NROW]; float X[NROW*66];
//   ushort Ch[NROW*64]; ushort Cl[NROW*64];
//   ushort Bf[2][128*2*64*8]   (B-fragment layout: [split][(lt*2+ks)*64+lane][8])
constexpr size_t F_C0S = 0;
constexpr size_t F_Z   = F_C0S + NROW;
constexpr size_t F_X   = F_Z + NROW;
constexpr size_t F_END = F_X + (size_t)NROW * XSTRIDE;
constexpr size_t U_CH  = 0;                       // ushort offsets after float region
constexpr size_t U_CL  = U_CH + (size_t)NROW * 64;
constexpr size_t U_BF  = U_CL + (size_t)NROW * 64;
constexpr size_t BF_SPLIT = (size_t)128 * 2 * 64 * 8;   // 131072

// ---------------------------------------------------------------- k0: basis frags
// Bf[split][(lt*2+ks)*64 + lane][j] = basisrow(ks*32 + (lane>>4)*8 + j, lt*16 + (lane&15))
// basisrow(r,t): r<32 -> cos(2pi(r+1)t/2048) ; else sin(2pi(r-31)t/2048)
__global__ void k0_basis(unsigned short* __restrict__ Bf) {
  int gid = blockIdx.x * 256 + threadIdx.x;      // [0, 16384)
  if (gid >= 16384) return;
  int lt = gid >> 7, rem = gid & 127, ks = rem >> 6, lane = rem & 63;
  int q = lane >> 4, n = lane & 15;
  int t = lt * 16 + n;
  size_t base = ((size_t)((lt * 2 + ks) * 64 + lane)) * 8;
  for (int j = 0; j < 8; ++j) {
    int kr = ks * 32 + q * 8 + j;
    int freq = (kr < 32) ? (kr + 1) : (kr - 31);
    int ph = (freq * t) & (CL - 1);
    float ang = (float)ph * (TWO_PI / (float)CL);
    float val = (kr < 32) ? cosf(ang) : sinf(ang);
    unsigned short hi = f2bf(val);
    unsigned short lo = f2bf(val - bf2f(hi));
    Bf[base + j] = hi;
    Bf[BF_SPLIT + base + j] = lo;
  }
}

// ---------------------------------------------------------------- k1: X_f (64-pt DFT)
__global__ void k1_dft(const float* __restrict__ q, const float* __restrict__ kin,
                       float* __restrict__ X) {
  __shared__ float qs[4][64], ks[4][64], twc[64], tws[64];
  int tid = threadIdx.x;
  if (tid < 64) {
    float ang = (float)tid * (TWO_PI / 64.0f);
    twc[tid] = cosf(ang);
    tws[tid] = sinf(ang);
  }
  int r = tid >> 6, lane = tid & 63;
  int row = blockIdx.x * 4 + r;
  int b = row >> 14, h = (row >> 11) & 7, s = row & 2047;
  size_t gofs = ((size_t)(b * CL + s)) * CE + h * 64 + lane;
  qs[r][lane] = q[gofs];
  ks[r][lane] = kin[gofs];
  __syncthreads();
  if (lane < 33) {
    float qr = 0, qi = 0, kr = 0, ki = 0;
    for (int c = 0; c < 64; ++c) {
      int idx = (lane * c) & 63;
      float cc = twc[idx], ss = tws[idx];
      float qv = qs[r][c], kv = ks[r][c];
      qr += qv * cc; qi -= qv * ss;
      kr += kv * cc; ki -= kv * ss;
    }
    float xre = qr * kr + qi * ki;
    float xim = qi * kr - qr * ki;
    X[(size_t)row * XSTRIDE + 2 * lane]     = xre;
    X[(size_t)row * XSTRIDE + 2 * lane + 1] = xim;
  }
}

// ---------------------------------------------------------------- k2: split coefs
__global__ void k2_coef(const float* __restrict__ X, unsigned short* __restrict__ Ch,
                        unsigned short* __restrict__ Cl, float* __restrict__ c0s) {
  __shared__ float mre[33], mim[33], lm[8 * 33], c0v[8];
  int tid = threadIdx.x;
  int bs = blockIdx.x;
  int b = bs >> 11, s = bs & 2047;
  if (tid < 33) {
    float sr = 0, si = 0;
    for (int h = 0; h < 8; ++h) {
      size_t row = (size_t)((b * 8 + h) * 2048 + s);
      sr += X[row * XSTRIDE + 2 * tid];
      si += X[row * XSTRIDE + 2 * tid + 1];
    }
    mre[tid] = sr * 0.125f;
    mim[tid] = si * 0.125f;
  }
  __syncthreads();
  for (int p = tid; p < 264; p += 256) {
    int h = p / 33, f = p - h * 33;
    size_t row = (size_t)((b * 8 + h) * 2048 + s);
    float yre = X[row * XSTRIDE + 2 * f] - mre[f];
    float yim = X[row * XSTRIDE + 2 * f + 1] - mim[f];
    if (f == 0) {
      float c0 = yre * SCALE;
      c0v[h] = c0;
      lm[h * 33] = fabsf(c0);
    } else {
      float a  =  2.0f * yre * SCALE;
      float bb = -2.0f * yim * SCALE;
      unsigned short ah = f2bf(a);
      Ch[row * 64 + (f - 1)] = ah;
      Cl[row * 64 + (f - 1)] = f2bf(a - bf2f(ah));
      unsigned short bh2 = f2bf(bb);
      Ch[row * 64 + 32 + (f - 1)] = bh2;
      Cl[row * 64 + 32 + (f - 1)] = f2bf(bb - bf2f(bh2));
      lm[h * 33 + f] = fabsf(a) + fabsf(bb);
    }
  }
  __syncthreads();
  if (tid < 8) {
    float m = 0;
    for (int f = 0; f < 33; ++f) m += lm[tid * 33 + f];
    size_t row = (size_t)((b * 8 + tid) * 2048 + s);
    c0s[row] = c0v[tid] - m;
  }
}

// ---------------------------------------------------------------- k3: Z via MFMA
// Block: 64 rows (4 waves x 16). A-frags in regs (loaded once); loop 128 l-tiles,
// B-frags from global (frag-layout, coalesced); 6 MFMA splits; exp; per-lane Z partials;
// shuffle-reduce across the 16 lanes of each quad-group. No atomics.
__launch_bounds__(256)
__global__ void k3_z(const unsigned short* __restrict__ Ch, const unsigned short* __restrict__ Cl,
                     const float* __restrict__ c0s, const unsigned short* __restrict__ Bf,
                     float* __restrict__ Z) {
  int tid = threadIdx.x;
  int w = tid >> 6, lane = tid & 63, q = lane >> 4, n = lane & 15;
  int rowbase = blockIdx.x * 64;
  int srow = rowbase + w * 16 + n;                 // A m-index = lane&15
  short8 Ah[2], Al[2];
#pragma unroll
  for (int ksp = 0; ksp < 2; ++ksp) {
    Ah[ksp] = *(const short8*)(Ch + (size_t)srow * 64 + ksp * 32 + q * 8);
    Al[ksp] = *(const short8*)(Cl + (size_t)srow * 64 + ksp * 32 + q * 8);
  }
  float c0r[4], zacc[4];
#pragma unroll
  for (int r = 0; r < 4; ++r) {
    c0r[r] = c0s[rowbase + w * 16 + q * 4 + r];
    zacc[r] = 0.0f;
  }
  const unsigned short* BfL = Bf + BF_SPLIT;
  for (int lt = 0; lt < 128; ++lt) {
    size_t b0 = ((size_t)(lt * 2 + 0) * 64 + lane) * 8;
    size_t b1 = ((size_t)(lt * 2 + 1) * 64 + lane) * 8;
    short8 Bh0 = *(const short8*)(Bf + b0);
    short8 Bh1 = *(const short8*)(Bf + b1);
    short8 Bl0 = *(const short8*)(BfL + b0);
    short8 Bl1 = *(const short8*)(BfL + b1);
    floatx4 acc = {0.f, 0.f, 0.f, 0.f};
    acc = __builtin_amdgcn_mfma_f32_16x16x32_bf16(Ah[0], Bh0, acc, 0, 0, 0);
    acc = __builtin_amdgcn_mfma_f32_16x16x32_bf16(Ah[1], Bh1, acc, 0, 0, 0);
    acc = __builtin_amdgcn_mfma_f32_16x16x32_bf16(Ah[0], Bl0, acc, 0, 0, 0);
    acc = __builtin_amdgcn_mfma_f32_16x16x32_bf16(Ah[1], Bl1, acc, 0, 0, 0);
    acc = __builtin_amdgcn_mfma_f32_16x16x32_bf16(Al[0], Bh0, acc, 0, 0, 0);
    acc = __builtin_amdgcn_mfma_f32_16x16x32_bf16(Al[1], Bh1, acc, 0, 0, 0);
#pragma unroll
    for (int r = 0; r < 4; ++r) zacc[r] += __expf(acc[r] + c0r[r]);
  }
#pragma unroll
  for (int r = 0; r < 4; ++r) {
#pragma unroll
    for (int m = 1; m < 16; m <<= 1) zacc[r] += __shfl_xor(zacc[r], m, 16);
  }
  if (n == 0) {
#pragma unroll
    for (int r = 0; r < 4; ++r) Z[rowbase + w * 16 + q * 4 + r] = zacc[r];
  }
}

// ---------------------------------------------------------------- k4: output
// Block: (b,h) x 64-l tile. B-frags in registers (16 b128). Loop 32 s-tiles:
//  stage Vs = v/Z (LDS), MFMA logits -> exp -> Es (bf16, LDS), then fp32 PV
//  (128 threads, 4d x 8l per thread, ratio 32 MAC per 2 b128 reads).
__launch_bounds__(256)
__global__ void k4_out(const unsigned short* __restrict__ Ch, const unsigned short* __restrict__ Cl,
                       const float* __restrict__ c0s, const float* __restrict__ Z,
                       const unsigned short* __restrict__ Bf, const float* __restrict__ values,
                       float* __restrict__ out) {
  __shared__ float Vs[64 * 64];
  __shared__ unsigned short Es[64 * 72];       // +8 pad to break write conflicts
  int tid = threadIdx.x;
  int w = tid >> 6, lane = tid & 63, q = lane >> 4, n = lane & 15;
  int bh = blockIdx.x, b = bh >> 3, h = bh & 7;
  int l0 = blockIdx.y * 64, lt0 = blockIdx.y * 4;
  const unsigned short* BfL = Bf + BF_SPLIT;
  short8 Bh[4][2], Bl[4][2];
#pragma unroll
  for (int lt = 0; lt < 4; ++lt)
#pragma unroll
    for (int ksp = 0; ksp < 2; ++ksp) {
      size_t bo = ((size_t)((lt0 + lt) * 2 + ksp) * 64 + lane) * 8;
      Bh[lt][ksp] = *(const short8*)(Bf + bo);
      Bl[lt][ksp] = *(const short8*)(BfL + bo);
    }
  int dg = tid >> 3, lg = tid & 7;             // PV mapping (tid<128)
  float acc[4][8];
#pragma unroll
  for (int i = 0; i < 4; ++i)
#pragma unroll
    for (int j = 0; j < 8; ++j) acc[i][j] = 0.0f;

  for (int stile = 0; stile < 32; ++stile) {
    int sb = stile * 64;
    int rowZ = bh * 2048 + sb;
    __syncthreads();                            // prev PV reads done
    {                                           // stage Vs = v / Z
      int sl = tid >> 2, dq = (tid & 3) * 16;
      float inv = 1.0f / Z[rowZ + sl];
      const float4* vp = (const float4*)(values + ((size_t)(b * CL + sb + sl)) * CE + h * 64 + dq);
      float4* dst = (float4*)(Vs + sl * 64 + dq);
#pragma unroll
      for (int m = 0; m < 4; ++m) {
        float4 t = vp[m];
        t.x *= inv; t.y *= inv; t.z *= inv; t.w *= inv;
        dst[m] = t;
      }
    }
    // E phase: MFMA logits + exp -> Es
    int srow = rowZ + w * 16 + n;
    short8 Ah[2], Al[2];
#pragma unroll
    for (int ksp = 0; ksp < 2; ++ksp) {
      Ah[ksp] = *(const short8*)(Ch + (size_t)srow * 64 + ksp * 32 + q * 8);
      Al[ksp] = *(const short8*)(Cl + (size_t)srow * 64 + ksp * 32 + q * 8);
    }
    float c0r[4];
#pragma unroll
    for (int r = 0; r < 4; ++r) c0r[r] = c0s[rowZ + w * 16 + q * 4 + r];
#pragma unroll
    for (int lt = 0; lt < 4; ++lt) {
      floatx4 y = {0.f, 0.f, 0.f, 0.f};
      y = __builtin_amdgcn_mfma_f32_16x16x32_bf16(Ah[0], Bh[lt][0], y, 0, 0, 0);
      y = __builtin_amdgcn_mfma_f32_16x16x32_bf16(Ah[1], Bh[lt][1], y, 0, 0, 0);
      y = __builtin_amdgcn_mfma_f32_16x16x32_bf16(Ah[0], Bl[lt][0], y, 0, 0, 0);
      y = __builtin_amdgcn_mfma_f32_16x16x32_bf16(Ah[1], Bl[lt][1], y, 0, 0, 0);
      y = __builtin_amdgcn_mfma_f32_16x16x32_bf16(Al[0], Bh[lt][0], y, 0, 0, 0);
      y = __builtin_amdgcn_mfma_f32_16x16x32_bf16(Al[1], Bh[lt][1], y, 0, 0, 0);
#pragma unroll
      for (int r = 0; r < 4; ++r) {
        float e = __expf(y[r] + c0r[r]);
        Es[(w * 16 + q * 4 + r) * 72 + lt * 16 + n] = f2bf(e);
      }
    }
    __syncthreads();                            // Es/Vs ready
    if (tid < 128) {                            // PV: 4d x 8l per thread
#pragma unroll 4
      for (int s = 0; s < 64; ++s) {
        float4 v4 = *(const float4*)(Vs + s * 64 + dg * 4);
        uint4 eu = *(const uint4*)(Es + s * 72 + lg * 8);
        float e0 = lo2f(eu.x), e1 = hi2f(eu.x);
        float e2 = lo2f(eu.y), e3 = hi2f(eu.y);
        float e4 = lo2f(eu.z), e5 = hi2f(eu.z);
        float e6 = lo2f(eu.w), e7 = hi2f(eu.w);
        float vv[4] = {v4.x, v4.y, v4.z, v4.w};
#pragma unroll
        for (int i = 0; i < 4; ++i) {
          acc[i][0] += vv[i] * e0; acc[i][1] += vv[i] * e1;
          acc[i][2] += vv[i] * e2; acc[i][3] += vv[i] * e3;
          acc[i][4] += vv[i] * e4; acc[i][5] += vv[i] * e5;
          acc[i][6] += vv[i] * e6; acc[i][7] += vv[i] * e7;
        }
      }
    }
  }
  if (tid < 128) {
#pragma unroll
    for (int i = 0; i < 4; ++i) {
      size_t base = ((size_t)((b * 64 + dg * 4 + i) * 8 + h)) * 2048 + l0 + lg * 8;
      float4 o1; o1.x = acc[i][0]; o1.y = acc[i][1]; o1.z = acc[i][2]; o1.w = acc[i][3];
      float4 o2; o2.x = acc[i][4]; o2.y = acc[i][5]; o2.z = acc[i][6]; o2.w = acc[i][7];
      *(float4*)(out + base) = o1;
      *(float4*)(out + base + 4) = o2;
    }
  }
}

extern "C" void kernel_launch(void* const* d_in, const int* in_sizes, int n_in,
                              void* d_out, int out_size, void* d_ws, size_t ws_size,
                              hipStream_t stream) {
  const float* q = (const float*)d_in[0];
  const float* k = (const float*)d_in[1];
  const float* v = (const float*)d_in[2];
  float* out = (float*)d_out;
  float* ws = (float*)d_ws;
  float* c0s = ws + F_C0S;
  float* Z   = ws + F_Z;
  float* X   = ws + F_X;
  unsigned short* ubase = (unsigned short*)(ws + F_END);
  unsigned short* Ch = ubase + U_CH;
  unsigned short* Cl = ubase + U_CL;
  unsigned short* Bf = ubase + U_BF;

  k0_basis<<<dim3(64), dim3(256), 0, stream>>>(Bf);
  k1_dft<<<dim3(8192), dim3(256), 0, stream>>>(q, k, X);
  k2_coef<<<dim3(4096), dim3(256), 0, stream>>>(X, Ch, Cl, c0s);
  k3_z<<<dim3(512), dim3(256), 0, stream>>>(Ch, Cl, c0s, Bf, Z);
  k4_out<<<dim3(16, 32), dim3(256), 0, stream>>>(Ch, Cl, c0s, Z, Bf, v, out);
}

// Round 3
// 245.909 us; speedup vs baseline: 1.9761x; 1.7126x over previous
//
#include <hip/hip_runtime.h>
#include <math.h>

// B=2, H=8, L=2048, E=512, d=64
constexpr int CL = 2048, CE = 512;
constexpr int NROW = 32768;                 // b*h*s rows
constexpr int XSTRIDE = 66;
constexpr float SCALE = 1.0f / 2048.0f;
constexpr float TWO_PI = 6.283185307179586f;

typedef short short8 __attribute__((ext_vector_type(8)));
typedef float floatx4 __attribute__((ext_vector_type(4)));

__device__ inline unsigned short f2bf(float f) {
  union { float f; unsigned u; } c; c.f = f;
  unsigned u = c.u + 0x7FFF + ((c.u >> 16) & 1);
  return (unsigned short)(u >> 16);
}
__device__ inline float bf2f(unsigned short h) {
  union { unsigned u; float f; } c; c.u = ((unsigned)h) << 16;
  return c.f;
}
// Swizzled LDS tile [64 rows][64 shorts]: 16B-group g at row r lands at g^(r&7).
// Rows are 128B (16B-aligned); writes along rows (b64) and fragment reads (b128)
// are both <=2-way bank-aliased (free).
__device__ inline int sw(int r, int o) {
  return r * 64 + ((((o >> 3) ^ r) & 7) << 3) + (o & 7);
}

// Workspace:
//   float c0s[NROW]; float invZ[NROW]; float X[NROW*66];
//   ushort Ch[NROW*64]; ushort Cl[NROW*64]; ushort Bf[2][128*2*64*8]
constexpr size_t F_C0S = 0;
constexpr size_t F_IZ  = F_C0S + NROW;
constexpr size_t F_X   = F_IZ + NROW;
constexpr size_t F_END = F_X + (size_t)NROW * XSTRIDE;
constexpr size_t U_CH  = 0;
constexpr size_t U_CL  = U_CH + (size_t)NROW * 64;
constexpr size_t U_BF  = U_CL + (size_t)NROW * 64;
constexpr size_t BF_SPLIT = (size_t)128 * 2 * 64 * 8;   // 131072

// ---------------------------------------------------------------- k0: basis frags
__global__ void k0_basis(unsigned short* __restrict__ Bf) {
  int gid = blockIdx.x * 256 + threadIdx.x;      // [0, 16384)
  if (gid >= 16384) return;
  int lt = gid >> 7, rem = gid & 127, ks = rem >> 6, lane = rem & 63;
  int q = lane >> 4, n = lane & 15;
  int t = lt * 16 + n;
  size_t base = ((size_t)((lt * 2 + ks) * 64 + lane)) * 8;
  for (int j = 0; j < 8; ++j) {
    int kr = ks * 32 + q * 8 + j;
    int freq = (kr < 32) ? (kr + 1) : (kr - 31);
    int ph = (freq * t) & (CL - 1);
    float ang = (float)ph * (TWO_PI / (float)CL);
    float val = (kr < 32) ? cosf(ang) : sinf(ang);
    unsigned short hi = f2bf(val);
    unsigned short lo = f2bf(val - bf2f(hi));
    Bf[base + j] = hi;
    Bf[BF_SPLIT + base + j] = lo;
  }
}

// ---------------------------------------------------------------- k1: X_f (64-pt DFT)
__global__ void k1_dft(const float* __restrict__ q, const float* __restrict__ kin,
                       float* __restrict__ X) {
  __shared__ float qs[4][64], ks[4][64], twc[64], tws[64];
  int tid = threadIdx.x;
  if (tid < 64) {
    float ang = (float)tid * (TWO_PI / 64.0f);
    twc[tid] = cosf(ang);
    tws[tid] = sinf(ang);
  }
  int r = tid >> 6, lane = tid & 63;
  int row = blockIdx.x * 4 + r;
  int b = row >> 14, h = (row >> 11) & 7, s = row & 2047;
  size_t gofs = ((size_t)(b * CL + s)) * CE + h * 64 + lane;
  qs[r][lane] = q[gofs];
  ks[r][lane] = kin[gofs];
  __syncthreads();
  if (lane < 33) {
    float qr = 0, qi = 0, kr = 0, ki = 0;
    for (int c = 0; c < 64; ++c) {
      int idx = (lane * c) & 63;
      float cc = twc[idx], ss = tws[idx];
      float qv = qs[r][c], kv = ks[r][c];
      qr += qv * cc; qi -= qv * ss;
      kr += kv * cc; ki -= kv * ss;
    }
    float xre = qr * kr + qi * ki;
    float xim = qi * kr - qr * ki;
    X[(size_t)row * XSTRIDE + 2 * lane]     = xre;
    X[(size_t)row * XSTRIDE + 2 * lane + 1] = xim;
  }
}

// ---------------------------------------------------------------- k2: split coefs
__global__ void k2_coef(const float* __restrict__ X, unsigned short* __restrict__ Ch,
                        unsigned short* __restrict__ Cl, float* __restrict__ c0s) {
  __shared__ float mre[33], mim[33], lm[8 * 33], c0v[8];
  int tid = threadIdx.x;
  int bs = blockIdx.x;
  int b = bs >> 11, s = bs & 2047;
  if (tid < 33) {
    float sr = 0, si = 0;
    for (int h = 0; h < 8; ++h) {
      size_t row = (size_t)((b * 8 + h) * 2048 + s);
      sr += X[row * XSTRIDE + 2 * tid];
      si += X[row * XSTRIDE + 2 * tid + 1];
    }
    mre[tid] = sr * 0.125f;
    mim[tid] = si * 0.125f;
  }
  __syncthreads();
  for (int p = tid; p < 264; p += 256) {
    int h = p / 33, f = p - h * 33;
    size_t row = (size_t)((b * 8 + h) * 2048 + s);
    float yre = X[row * XSTRIDE + 2 * f] - mre[f];
    float yim = X[row * XSTRIDE + 2 * f + 1] - mim[f];
    if (f == 0) {
      float c0 = yre * SCALE;
      c0v[h] = c0;
      lm[h * 33] = fabsf(c0);
    } else {
      float a  =  2.0f * yre * SCALE;
      float bb = -2.0f * yim * SCALE;
      unsigned short ah = f2bf(a);
      Ch[row * 64 + (f - 1)] = ah;
      Cl[row * 64 + (f - 1)] = f2bf(a - bf2f(ah));
      unsigned short bh2 = f2bf(bb);
      Ch[row * 64 + 32 + (f - 1)] = bh2;
      Cl[row * 64 + 32 + (f - 1)] = f2bf(bb - bf2f(bh2));
      lm[h * 33 + f] = fabsf(a) + fabsf(bb);
    }
  }
  __syncthreads();
  if (tid < 8) {
    float m = 0;
    for (int f = 0; f < 33; ++f) m += lm[tid * 33 + f];
    size_t row = (size_t)((b * 8 + tid) * 2048 + s);
    c0s[row] = c0v[tid] - m;
  }
}

// ---------------------------------------------------------------- k3: invZ via MFMA
// Block = 64 rows. Waves SPLIT the l dimension (lt = w, w+4, ...) so B-frag
// global reads are not duplicated; A-coefs for all 64 rows replicated in regs.
__launch_bounds__(256)
__global__ void k3_z(const unsigned short* __restrict__ Ch, const unsigned short* __restrict__ Cl,
                     const float* __restrict__ c0s, const unsigned short* __restrict__ Bf,
                     float* __restrict__ invZ) {
  __shared__ float Zl[64];
  int tid = threadIdx.x;
  int w = tid >> 6, lane = tid & 63, q = lane >> 4, n = lane & 15;
  int rowbase = blockIdx.x * 64;
  short8 Ah[4][2], Al[4][2];
#pragma unroll
  for (int c = 0; c < 4; ++c)
#pragma unroll
    for (int ksp = 0; ksp < 2; ++ksp) {
      size_t srow = (size_t)(rowbase + c * 16 + n);
      Ah[c][ksp] = *(const short8*)(Ch + srow * 64 + ksp * 32 + q * 8);
      Al[c][ksp] = *(const short8*)(Cl + srow * 64 + ksp * 32 + q * 8);
    }
  float c0r[4][4], zacc[4][4];
#pragma unroll
  for (int c = 0; c < 4; ++c)
#pragma unroll
    for (int r = 0; r < 4; ++r) {
      c0r[c][r] = c0s[rowbase + c * 16 + q * 4 + r];
      zacc[c][r] = 0.0f;
    }
  if (tid < 64) Zl[tid] = 0.0f;
  const unsigned short* BfL = Bf + BF_SPLIT;
  for (int lt = w; lt < 128; lt += 4) {
    size_t b0 = ((size_t)(lt * 2 + 0) * 64 + lane) * 8;
    size_t b1 = ((size_t)(lt * 2 + 1) * 64 + lane) * 8;
    short8 Bh0 = *(const short8*)(Bf + b0);
    short8 Bh1 = *(const short8*)(Bf + b1);
    short8 Bl0 = *(const short8*)(BfL + b0);
    short8 Bl1 = *(const short8*)(BfL + b1);
#pragma unroll
    for (int c = 0; c < 4; ++c) {
      floatx4 y = {0.f, 0.f, 0.f, 0.f};
      y = __builtin_amdgcn_mfma_f32_16x16x32_bf16(Ah[c][0], Bh0, y, 0, 0, 0);
      y = __builtin_amdgcn_mfma_f32_16x16x32_bf16(Ah[c][1], Bh1, y, 0, 0, 0);
      y = __builtin_amdgcn_mfma_f32_16x16x32_bf16(Ah[c][0], Bl0, y, 0, 0, 0);
      y = __builtin_amdgcn_mfma_f32_16x16x32_bf16(Ah[c][1], Bl1, y, 0, 0, 0);
      y = __builtin_amdgcn_mfma_f32_16x16x32_bf16(Al[c][0], Bh0, y, 0, 0, 0);
      y = __builtin_amdgcn_mfma_f32_16x16x32_bf16(Al[c][1], Bh1, y, 0, 0, 0);
#pragma unroll
      for (int r = 0; r < 4; ++r) zacc[c][r] += __expf(y[r] + c0r[c][r]);
    }
  }
  __syncthreads();       // Zl zero-init visible
#pragma unroll
  for (int c = 0; c < 4; ++c)
#pragma unroll
    for (int r = 0; r < 4; ++r) {
#pragma unroll
      for (int m = 1; m < 16; m <<= 1) zacc[c][r] += __shfl_xor(zacc[c][r], m, 16);
      if (n == 0) atomicAdd(&Zl[c * 16 + q * 4 + r], zacc[c][r]);
    }
  __syncthreads();
  if (tid < 64) invZ[rowbase + tid] = 1.0f / Zl[tid];
}

// ---------------------------------------------------------------- k4: output
// Block = (b,h) x 64 l-cols, loop 32 s-tiles of 64.
// E-phase: logits via MFMA (basis frags in regs), exp * invZ -> Es [l][s] bf16 (swizzled).
// PV-phase: wave w owns d-chunk w: Out[l,d] += E[l,s] @ Vsplit[s,d] via MFMA.
__launch_bounds__(256)
__global__ void k4_out(const unsigned short* __restrict__ Ch, const unsigned short* __restrict__ Cl,
                       const float* __restrict__ c0s, const float* __restrict__ invZ,
                       const unsigned short* __restrict__ Bf, const float* __restrict__ values,
                       float* __restrict__ out) {
  __shared__ unsigned short Es[64 * 64];   // [l][s] swizzled
  __shared__ unsigned short Vh[64 * 64];   // [d][s] swizzled, bf16 hi
  __shared__ unsigned short Vl[64 * 64];   // [d][s] swizzled, bf16 lo
  int tid = threadIdx.x;
  int w = tid >> 6, lane = tid & 63, q = lane >> 4, n = lane & 15;
  int bh = blockIdx.x, b = bh >> 3, h = bh & 7;
  int l0 = blockIdx.y * 64, lt0 = blockIdx.y * 4;
  const unsigned short* BfL = Bf + BF_SPLIT;
  short8 Bbh[4][2], Bbl[4][2];
#pragma unroll
  for (int lt = 0; lt < 4; ++lt)
#pragma unroll
    for (int ksp = 0; ksp < 2; ++ksp) {
      size_t bo = ((size_t)((lt0 + lt) * 2 + ksp) * 64 + lane) * 8;
      Bbh[lt][ksp] = *(const short8*)(Bf + bo);
      Bbl[lt][ksp] = *(const short8*)(BfL + bo);
    }
  floatx4 accv[4];
#pragma unroll
  for (int lt = 0; lt < 4; ++lt) accv[lt] = (floatx4){0.f, 0.f, 0.f, 0.f};
  int vd = tid & 63, vsq = tid >> 6;

  for (int st = 0; st < 32; ++st) {
    int sb = st * 64;
    int rowZ = bh * 2048 + sb;
    __syncthreads();                       // prev PV reads done
    {                                      // stage V (transposed, bf16 split)
      const float* vsrc = values + ((size_t)(b * CL + sb + vsq * 16)) * CE + h * 64 + vd;
#pragma unroll
      for (int g4 = 0; g4 < 4; ++g4) {
        unsigned short ph[4], pl[4];
#pragma unroll
        for (int m = 0; m < 4; ++m) {
          float f = vsrc[(size_t)(g4 * 4 + m) * CE];
          unsigned short hi = f2bf(f);
          ph[m] = hi; pl[m] = f2bf(f - bf2f(hi));
        }
        uint2 vh2, vl2;
        vh2.x = (unsigned)ph[0] | ((unsigned)ph[1] << 16);
        vh2.y = (unsigned)ph[2] | ((unsigned)ph[3] << 16);
        vl2.x = (unsigned)pl[0] | ((unsigned)pl[1] << 16);
        vl2.y = (unsigned)pl[2] | ((unsigned)pl[3] << 16);
        int o = vsq * 16 + g4 * 4;
        *(uint2*)(Vh + sw(vd, o)) = vh2;
        *(uint2*)(Vl + sw(vd, o)) = vl2;
      }
    }
    // E-phase
    {
      size_t srow = (size_t)(rowZ + w * 16 + n);
      short8 Ah[2], Al[2];
#pragma unroll
      for (int ksp = 0; ksp < 2; ++ksp) {
        Ah[ksp] = *(const short8*)(Ch + srow * 64 + ksp * 32 + q * 8);
        Al[ksp] = *(const short8*)(Cl + srow * 64 + ksp * 32 + q * 8);
      }
      float c0r[4], izr[4];
#pragma unroll
      for (int r = 0; r < 4; ++r) {
        c0r[r] = c0s[rowZ + w * 16 + q * 4 + r];
        izr[r] = invZ[rowZ + w * 16 + q * 4 + r];
      }
#pragma unroll
      for (int lt = 0; lt < 4; ++lt) {
        floatx4 y = {0.f, 0.f, 0.f, 0.f};
        y = __builtin_amdgcn_mfma_f32_16x16x32_bf16(Ah[0], Bbh[lt][0], y, 0, 0, 0);
        y = __builtin_amdgcn_mfma_f32_16x16x32_bf16(Ah[1], Bbh[lt][1], y, 0, 0, 0);
        y = __builtin_amdgcn_mfma_f32_16x16x32_bf16(Ah[0], Bbl[lt][0], y, 0, 0, 0);
        y = __builtin_amdgcn_mfma_f32_16x16x32_bf16(Ah[1], Bbl[lt][1], y, 0, 0, 0);
        y = __builtin_amdgcn_mfma_f32_16x16x32_bf16(Al[0], Bbh[lt][0], y, 0, 0, 0);
        y = __builtin_amdgcn_mfma_f32_16x16x32_bf16(Al[1], Bbh[lt][1], y, 0, 0, 0);
        unsigned short er[4];
#pragma unroll
        for (int r = 0; r < 4; ++r) er[r] = f2bf(__expf(y[r] + c0r[r]) * izr[r]);
        uint2 e2;
        e2.x = (unsigned)er[0] | ((unsigned)er[1] << 16);
        e2.y = (unsigned)er[2] | ((unsigned)er[3] << 16);
        *(uint2*)(Es + sw(lt * 16 + n, w * 16 + q * 4)) = e2;
      }
    }
    __syncthreads();                       // Es/Vh/Vl ready
    // PV-phase: wave w -> d-chunk w
#pragma unroll
    for (int kc = 0; kc < 2; ++kc) {
      int s0 = kc * 32;
      short8 Bvh = *(const short8*)(Vh + sw(w * 16 + n, s0 + q * 8));
      short8 Bvl = *(const short8*)(Vl + sw(w * 16 + n, s0 + q * 8));
#pragma unroll
      for (int lt = 0; lt < 4; ++lt) {
        short8 Ef = *(const short8*)(Es + sw(lt * 16 + n, s0 + q * 8));
        accv[lt] = __builtin_amdgcn_mfma_f32_16x16x32_bf16(Ef, Bvh, accv[lt], 0, 0, 0);
        accv[lt] = __builtin_amdgcn_mfma_f32_16x16x32_bf16(Ef, Bvl, accv[lt], 0, 0, 0);
      }
    }
  }
  // Store: lane holds D[l = lt*16+q*4+r][d = w*16+n]; out layout [b][d][h][l].
#pragma unroll
  for (int lt = 0; lt < 4; ++lt) {
    size_t base = ((size_t)((b * 64 + w * 16 + n) * 8 + h)) * 2048 + l0 + lt * 16 + q * 4;
    float4 o4;
    o4.x = accv[lt][0]; o4.y = accv[lt][1]; o4.z = accv[lt][2]; o4.w = accv[lt][3];
    *(float4*)(out + base) = o4;
  }
}

extern "C" void kernel_launch(void* const* d_in, const int* in_sizes, int n_in,
                              void* d_out, int out_size, void* d_ws, size_t ws_size,
                              hipStream_t stream) {
  const float* q = (const float*)d_in[0];
  const float* k = (const float*)d_in[1];
  const float* v = (const float*)d_in[2];
  float* out = (float*)d_out;
  float* ws = (float*)d_ws;
  float* c0s = ws + F_C0S;
  float* invZ = ws + F_IZ;
  float* X   = ws + F_X;
  unsigned short* ubase = (unsigned short*)(ws + F_END);
  unsigned short* Ch = ubase + U_CH;
  unsigned short* Cl = ubase + U_CL;
  unsigned short* Bf = ubase + U_BF;

  k0_basis<<<dim3(64), dim3(256), 0, stream>>>(Bf);
  k1_dft<<<dim3(8192), dim3(256), 0, stream>>>(q, k, X);
  k2_coef<<<dim3(4096), dim3(256), 0, stream>>>(X, Ch, Cl, c0s);
  k3_z<<<dim3(512), dim3(256), 0, stream>>>(Ch, Cl, c0s, Bf, invZ);
  k4_out<<<dim3(16, 32), dim3(256), 0, stream>>>(Ch, Cl, c0s, invZ, Bf, v, out);
}

// Round 4
// 207.138 us; speedup vs baseline: 2.3459x; 1.1872x over previous
//
#include <hip/hip_runtime.h>
#include <math.h>

// B=2, H=8, L=2048, E=512, d=64
constexpr int CL = 2048, CE = 512;
constexpr int NROW = 32768;                 // b*h*s rows
constexpr float SCALE = 1.0f / 2048.0f;
constexpr float TWO_PI = 6.283185307179586f;

typedef short short8 __attribute__((ext_vector_type(8)));
typedef float floatx4 __attribute__((ext_vector_type(4)));

__device__ inline unsigned short f2bf(float f) {
  union { float f; unsigned u; } c; c.f = f;
  unsigned u = c.u + 0x7FFF + ((c.u >> 16) & 1);
  return (unsigned short)(u >> 16);
}
__device__ inline float bf2f(unsigned short h) {
  union { unsigned u; float f; } c; c.u = ((unsigned)h) << 16;
  return c.f;
}

// ---------------- workspace layout ----------------
// floats:  c0s[NROW] | c0z[NROW] | X2[2][2048][8][66]   (X2 aliased by Vf after k2)
// ushorts: Ch[NROW*64] | Cl[NROW*64] | Bf[2][128*2*64*8] | Tw[4][2048]
constexpr size_t F_C0S = 0;
constexpr size_t F_C0Z = F_C0S + NROW;
constexpr size_t F_X   = F_C0Z + NROW;
constexpr size_t F_END = F_X + (size_t)NROW * 66;
constexpr size_t U_CH  = 0;
constexpr size_t U_CL  = U_CH + (size_t)NROW * 64;
constexpr size_t U_BF  = U_CL + (size_t)NROW * 64;
constexpr size_t U_TW  = U_BF + (size_t)2 * 128 * 2 * 64 * 8;
constexpr size_t BF_SPLIT = (size_t)128 * 2 * 64 * 8;   // 131072
constexpr size_t VF_PLANE = (size_t)16 * 32 * 8 * 512;  // 2097152 (fits in X2 region w/ hi+lo)

// ---------------------------------------------------------------- k0: basis frags
// Bf[split][(lt*2+ks)*64 + lane][j] = basisrow(ks*32 + quad*8 + j, lt*16 + n)
__global__ void k0_basis(unsigned short* __restrict__ Bf) {
  int gid = blockIdx.x * 256 + threadIdx.x;      // [0, 16384)
  if (gid >= 16384) return;
  int lt = gid >> 7, rem = gid & 127, ks = rem >> 6, lane = rem & 63;
  int q = lane >> 4, n = lane & 15;
  int t = lt * 16 + n;
  size_t base = ((size_t)((lt * 2 + ks) * 64 + lane)) * 8;
  for (int j = 0; j < 8; ++j) {
    int kr = ks * 32 + q * 8 + j;
    int freq = (kr < 32) ? (kr + 1) : (kr - 31);
    int ph = (freq * t) & (CL - 1);
    float ang = (float)ph * (TWO_PI / (float)CL);
    float val = (kr < 32) ? cosf(ang) : sinf(ang);
    unsigned short hi = f2bf(val);
    unsigned short lo = f2bf(val - bf2f(hi));
    Bf[base + j] = hi;
    Bf[BF_SPLIT + base + j] = lo;
  }
}

// ---------------------------------------------------------------- k0b: DFT twiddle frags
// Planes: 0=re_hi 1=re_lo 2=im_hi 3=im_lo, each [ct(2)][ksp(2)][lane(64)][j(8)] = 2048.
// re = cos(2pi f c/64), im = -sin(2pi f c/64); f = ct*16+n, c = ksp*32+quad*8+j.
__global__ void k0b_tw(unsigned short* __restrict__ Tw) {
  int gid = blockIdx.x * 256 + threadIdx.x;      // [0, 2048)
  if (gid >= 2048) return;
  int j = gid & 7, lane = (gid >> 3) & 63, ksp = (gid >> 9) & 1, ct = gid >> 10;
  int f = ct * 16 + (lane & 15);
  int c = ksp * 32 + ((lane >> 4) & 3) * 8 + j;
  float ang = (float)((f * c) & 63) * (TWO_PI / 64.0f);
  float re = cosf(ang), im = -sinf(ang);
  unsigned short rh = f2bf(re), ih = f2bf(im);
  Tw[gid]        = rh;
  Tw[2048 + gid] = f2bf(re - bf2f(rh));
  Tw[4096 + gid] = ih;
  Tw[6144 + gid] = f2bf(im - bf2f(ih));
}

// ---------------------------------------------------------------- k1: DFT via MFMA
// Block = 64 rows (4 waves x 16). Per wave: A = q/k rows (bf16-split), B = Tw frags.
// 4 accs (Qre,Qim,Kre,Kim) x 2 ct-tiles; f=32 (real Nyquist) via alternating sums.
// Writes X2[b][s][h][2f..2f+1] (re,im interleaved) -> k2 reads contiguously.
__launch_bounds__(256)
__global__ void k1_dft(const float* __restrict__ q, const float* __restrict__ kin,
                       const unsigned short* __restrict__ Tw, float* __restrict__ X2) {
  int tid = threadIdx.x;
  int w = tid >> 6, lane = tid & 63, qd = lane >> 4, n = lane & 15;
  int rowbase = blockIdx.x * 64;
  int growA = rowbase + w * 16 + n;
  int b = growA >> 14, h = (growA >> 11) & 7, s = growA & 2047;
  const float* qp = q + ((size_t)(b * 2048 + s)) * 512 + h * 64 + qd * 8;
  const float* kp = kin + ((size_t)(b * 2048 + s)) * 512 + h * 64 + qd * 8;
  float qv[16], kv[16];
#pragma unroll
  for (int ksp = 0; ksp < 2; ++ksp) {
    float4 a0 = *(const float4*)(qp + ksp * 32);
    float4 a1 = *(const float4*)(qp + ksp * 32 + 4);
    float4 b0 = *(const float4*)(kp + ksp * 32);
    float4 b1 = *(const float4*)(kp + ksp * 32 + 4);
    qv[ksp*8+0]=a0.x; qv[ksp*8+1]=a0.y; qv[ksp*8+2]=a0.z; qv[ksp*8+3]=a0.w;
    qv[ksp*8+4]=a1.x; qv[ksp*8+5]=a1.y; qv[ksp*8+6]=a1.z; qv[ksp*8+7]=a1.w;
    kv[ksp*8+0]=b0.x; kv[ksp*8+1]=b0.y; kv[ksp*8+2]=b0.z; kv[ksp*8+3]=b0.w;
    kv[ksp*8+4]=b1.x; kv[ksp*8+5]=b1.y; kv[ksp*8+6]=b1.z; kv[ksp*8+7]=b1.w;
  }
  // f=32: Q32 = sum (-1)^c q_c (real); parity of c = j&1
  float aq = 0.0f, ak = 0.0f;
#pragma unroll
  for (int i = 0; i < 16; ++i) {
    float sg = (i & 1) ? -1.0f : 1.0f;
    aq += sg * qv[i]; ak += sg * kv[i];
  }
  aq += __shfl_xor(aq, 16); aq += __shfl_xor(aq, 32);
  ak += __shfl_xor(ak, 16); ak += __shfl_xor(ak, 32);
  // bf16 splits of A
  short8 Aqh[2], Aql[2], Akh[2], Akl[2];
#pragma unroll
  for (int ksp = 0; ksp < 2; ++ksp) {
#pragma unroll
    for (int j = 0; j < 8; ++j) {
      unsigned short hq = f2bf(qv[ksp*8+j]);
      Aqh[ksp][j] = (short)hq; Aql[ksp][j] = (short)f2bf(qv[ksp*8+j] - bf2f(hq));
      unsigned short hk = f2bf(kv[ksp*8+j]);
      Akh[ksp][j] = (short)hk; Akl[ksp][j] = (short)f2bf(kv[ksp*8+j] - bf2f(hk));
    }
  }
#pragma unroll
  for (int ct = 0; ct < 2; ++ct) {
    short8 Brh[2], Brl[2], Bih[2], Bil[2];
#pragma unroll
    for (int ksp = 0; ksp < 2; ++ksp) {
      size_t off = (size_t)ct * 1024 + ksp * 512 + lane * 8;
      Brh[ksp] = *(const short8*)(Tw + off);
      Brl[ksp] = *(const short8*)(Tw + 2048 + off);
      Bih[ksp] = *(const short8*)(Tw + 4096 + off);
      Bil[ksp] = *(const short8*)(Tw + 6144 + off);
    }
    floatx4 qre = {0,0,0,0}, qim = {0,0,0,0}, kre = {0,0,0,0}, kim = {0,0,0,0};
#pragma unroll
    for (int ksp = 0; ksp < 2; ++ksp) {
      qre = __builtin_amdgcn_mfma_f32_16x16x32_bf16(Aqh[ksp], Brh[ksp], qre, 0,0,0);
      qre = __builtin_amdgcn_mfma_f32_16x16x32_bf16(Aqh[ksp], Brl[ksp], qre, 0,0,0);
      qre = __builtin_amdgcn_mfma_f32_16x16x32_bf16(Aql[ksp], Brh[ksp], qre, 0,0,0);
      qim = __builtin_amdgcn_mfma_f32_16x16x32_bf16(Aqh[ksp], Bih[ksp], qim, 0,0,0);
      qim = __builtin_amdgcn_mfma_f32_16x16x32_bf16(Aqh[ksp], Bil[ksp], qim, 0,0,0);
      qim = __builtin_amdgcn_mfma_f32_16x16x32_bf16(Aql[ksp], Bih[ksp], qim, 0,0,0);
      kre = __builtin_amdgcn_mfma_f32_16x16x32_bf16(Akh[ksp], Brh[ksp], kre, 0,0,0);
      kre = __builtin_amdgcn_mfma_f32_16x16x32_bf16(Akh[ksp], Brl[ksp], kre, 0,0,0);
      kre = __builtin_amdgcn_mfma_f32_16x16x32_bf16(Akl[ksp], Brh[ksp], kre, 0,0,0);
      kim = __builtin_amdgcn_mfma_f32_16x16x32_bf16(Akh[ksp], Bih[ksp], kim, 0,0,0);
      kim = __builtin_amdgcn_mfma_f32_16x16x32_bf16(Akh[ksp], Bil[ksp], kim, 0,0,0);
      kim = __builtin_amdgcn_mfma_f32_16x16x32_bf16(Akl[ksp], Bih[ksp], kim, 0,0,0);
    }
#pragma unroll
    for (int r = 0; r < 4; ++r) {
      int growC = rowbase + w * 16 + qd * 4 + r;
      int bc = growC >> 14, hc = (growC >> 11) & 7, sc = growC & 2047;
      int f = ct * 16 + n;
      float2 x;
      x.x = qre[r] * kre[r] + qim[r] * kim[r];
      x.y = qim[r] * kre[r] - qre[r] * kim[r];
      *(float2*)(X2 + (((size_t)(bc * 2048 + sc)) * 8 + hc) * 66 + 2 * f) = x;
    }
  }
  if (qd == 0) {
    float2 x; x.x = aq * ak; x.y = 0.0f;
    *(float2*)(X2 + (((size_t)(b * 2048 + s)) * 8 + h) * 66 + 64) = x;
  }
}

// ---------------------------------------------------------------- k2: split coefs
// Block per (b,s): X2 read fully coalesced (offset = 2p).
__global__ void k2_coef(const float* __restrict__ X2, unsigned short* __restrict__ Ch,
                        unsigned short* __restrict__ Cl, float* __restrict__ c0s) {
  __shared__ float sre[264], sim[264], lm[264], mre[33], mim[33], c0v[8];
  int tid = threadIdx.x;
  int bs = blockIdx.x;
  int b = bs >> 11, s = bs & 2047;
  for (int p = tid; p < 264; p += 256) {
    float2 v = *(const float2*)(X2 + (size_t)bs * 528 + 2 * p);
    sre[p] = v.x; sim[p] = v.y;
  }
  __syncthreads();
  if (tid < 33) {
    float r = 0, i2 = 0;
#pragma unroll
    for (int h = 0; h < 8; ++h) { r += sre[h * 33 + tid]; i2 += sim[h * 33 + tid]; }
    mre[tid] = r * 0.125f; mim[tid] = i2 * 0.125f;
  }
  __syncthreads();
  for (int p = tid; p < 264; p += 256) {
    int h = p / 33, f = p - h * 33;
    float yre = sre[p] - mre[f];
    float yim = sim[p] - mim[f];
    size_t row = (size_t)((b * 8 + h) * 2048 + s);
    if (f == 0) {
      float c0 = yre * SCALE;
      c0v[h] = c0;
      lm[p] = fabsf(c0);
    } else {
      float a  =  2.0f * yre * SCALE;
      float bb = -2.0f * yim * SCALE;
      unsigned short ah = f2bf(a);
      Ch[row * 64 + (f - 1)] = ah;
      Cl[row * 64 + (f - 1)] = f2bf(a - bf2f(ah));
      unsigned short bh2 = f2bf(bb);
      Ch[row * 64 + 32 + (f - 1)] = bh2;
      Cl[row * 64 + 32 + (f - 1)] = f2bf(bb - bf2f(bh2));
      lm[p] = fabsf(a) + fabsf(bb);
    }
  }
  __syncthreads();
  if (tid < 8) {
    float m = 0;
#pragma unroll
    for (int f = 0; f < 33; ++f) m += lm[tid * 33 + f];
    size_t row = (size_t)((b * 8 + tid) * 2048 + s);
    c0s[row] = c0v[tid] - m;
  }
}

// ---------------------------------------------------------------- kv: V frags (hi/lo)
// Per (bh, st): load V tile [64 s][64 d] (coalesced), LDS transpose (stride 65),
// emit MFMA B-frag layout: Vf[plane][((bh*32+st)*8 + dt*2+ksp)*512 + lane*8 + j].
__global__ void kv_frag(const float* __restrict__ values, unsigned short* __restrict__ Vf) {
  __shared__ float Vt[64 * 65];
  int tid = threadIdx.x;
  int bh = blockIdx.x, st = blockIdx.y;
  int b = bh >> 3, h = bh & 7;
  {
    int sl = tid >> 2, dq = (tid & 3) * 16;
    const float4* src = (const float4*)(values + ((size_t)(b * 2048 + st * 64 + sl)) * 512 + h * 64 + dq);
#pragma unroll
    for (int m = 0; m < 4; ++m) {
      float4 t = src[m];
      int base = sl * 65 + dq + m * 4;
      Vt[base] = t.x; Vt[base + 1] = t.y; Vt[base + 2] = t.z; Vt[base + 3] = t.w;
    }
  }
  __syncthreads();
#pragma unroll
  for (int iter = 0; iter < 2; ++iter) {
    int it = iter * 256 + tid;
    int lane = it & 63, ksp = (it >> 6) & 1, dt = it >> 7;
    int qd = lane >> 4, n = lane & 15;
    int d = dt * 16 + n;
    short8 hi, lo;
#pragma unroll
    for (int j = 0; j < 8; ++j) {
      float f = Vt[(ksp * 32 + qd * 8 + j) * 65 + d];
      unsigned short h2 = f2bf(f);
      hi[j] = (short)h2; lo[j] = (short)f2bf(f - bf2f(h2));
    }
    size_t off = (((size_t)(bh * 32 + st)) * 8 + dt * 2 + ksp) * 512 + lane * 8;
    *(short8*)(Vf + off) = hi;
    *(short8*)(Vf + VF_PLANE + off) = lo;
  }
}

// ---------------------------------------------------------------- k3: c0z = c0 - log(Z)
__launch_bounds__(256)
__global__ void k3_z(const unsigned short* __restrict__ Ch, const unsigned short* __restrict__ Cl,
                     const float* __restrict__ c0s, const unsigned short* __restrict__ Bf,
                     float* __restrict__ c0z) {
  __shared__ float Zl[64];
  int tid = threadIdx.x;
  int w = tid >> 6, lane = tid & 63, q = lane >> 4, n = lane & 15;
  int rowbase = blockIdx.x * 64;
  short8 Ah[4][2], Al[4][2];
#pragma unroll
  for (int c = 0; c < 4; ++c)
#pragma unroll
    for (int ksp = 0; ksp < 2; ++ksp) {
      size_t srow = (size_t)(rowbase + c * 16 + n);
      Ah[c][ksp] = *(const short8*)(Ch + srow * 64 + ksp * 32 + q * 8);
      Al[c][ksp] = *(const short8*)(Cl + srow * 64 + ksp * 32 + q * 8);
    }
  float c0r[4][4], zacc[4][4];
#pragma unroll
  for (int c = 0; c < 4; ++c)
#pragma unroll
    for (int r = 0; r < 4; ++r) {
      c0r[c][r] = c0s[rowbase + c * 16 + q * 4 + r];
      zacc[c][r] = 0.0f;
    }
  if (tid < 64) Zl[tid] = 0.0f;
  const unsigned short* BfL = Bf + BF_SPLIT;
  for (int lt = w; lt < 128; lt += 4) {
    size_t b0 = ((size_t)(lt * 2 + 0) * 64 + lane) * 8;
    size_t b1 = ((size_t)(lt * 2 + 1) * 64 + lane) * 8;
    short8 Bh0 = *(const short8*)(Bf + b0);
    short8 Bh1 = *(const short8*)(Bf + b1);
    short8 Bl0 = *(const short8*)(BfL + b0);
    short8 Bl1 = *(const short8*)(BfL + b1);
#pragma unroll
    for (int c = 0; c < 4; ++c) {
      floatx4 y = {0.f, 0.f, 0.f, 0.f};
      y = __builtin_amdgcn_mfma_f32_16x16x32_bf16(Ah[c][0], Bh0, y, 0, 0, 0);
      y = __builtin_amdgcn_mfma_f32_16x16x32_bf16(Ah[c][1], Bh1, y, 0, 0, 0);
      y = __builtin_amdgcn_mfma_f32_16x16x32_bf16(Ah[c][0], Bl0, y, 0, 0, 0);
      y = __builtin_amdgcn_mfma_f32_16x16x32_bf16(Ah[c][1], Bl1, y, 0, 0, 0);
      y = __builtin_amdgcn_mfma_f32_16x16x32_bf16(Al[c][0], Bh0, y, 0, 0, 0);
      y = __builtin_amdgcn_mfma_f32_16x16x32_bf16(Al[c][1], Bh1, y, 0, 0, 0);
#pragma unroll
      for (int r = 0; r < 4; ++r) zacc[c][r] += __expf(y[r] + c0r[c][r]);
    }
  }
  __syncthreads();
#pragma unroll
  for (int c = 0; c < 4; ++c)
#pragma unroll
    for (int r = 0; r < 4; ++r) {
#pragma unroll
      for (int m = 1; m < 16; m <<= 1) zacc[c][r] += __shfl_xor(zacc[c][r], m, 16);
      if (n == 0) atomicAdd(&Zl[c * 16 + q * 4 + r], zacc[c][r]);
    }
  __syncthreads();
  if (tid < 64) c0z[rowbase + tid] = c0s[rowbase + tid] - __logf(Zl[tid]);
}

// ---------------------------------------------------------------- k4: output
// Block = (b,h) x 32 l-cols; loop 32 s-tiles. LDS = double-buffered Es only.
// E-phase: logits via MFMA (basis frags in regs), E = exp(y + c0z) -> Es bf16.
// PV-phase: A = Es (LDS), B = Vf (global frags). One barrier per s-tile.
__launch_bounds__(256)
__global__ void k4_out(const unsigned short* __restrict__ Ch, const unsigned short* __restrict__ Cl,
                       const float* __restrict__ c0z, const unsigned short* __restrict__ Bf,
                       const unsigned short* __restrict__ Vf, float* __restrict__ out) {
  __shared__ unsigned short Es[2][32 * 72];    // [l][s], row stride 72 (2-way max alias)
  int tid = threadIdx.x;
  int w = tid >> 6, lane = tid & 63, qd = lane >> 4, n = lane & 15;
  int bh = blockIdx.x, b = bh >> 3, h = bh & 7;
  int l0 = blockIdx.y * 32, lt0 = blockIdx.y * 2;
  const unsigned short* BfL = Bf + BF_SPLIT;
  const unsigned short* VfL = Vf + VF_PLANE;
  short8 Bbh[2][2], Bbl[2][2];
#pragma unroll
  for (int lt = 0; lt < 2; ++lt)
#pragma unroll
    for (int ksp = 0; ksp < 2; ++ksp) {
      size_t bo = ((size_t)((lt0 + lt) * 2 + ksp) * 64 + lane) * 8;
      Bbh[lt][ksp] = *(const short8*)(Bf + bo);
      Bbl[lt][ksp] = *(const short8*)(BfL + bo);
    }
  floatx4 accv[2];
  accv[0] = (floatx4){0.f, 0.f, 0.f, 0.f};
  accv[1] = (floatx4){0.f, 0.f, 0.f, 0.f};

  for (int st = 0; st < 32; ++st) {
    int rowZ = bh * 2048 + st * 64;
    int p = st & 1;
    // E-phase
    size_t srow = (size_t)(rowZ + w * 16 + n);
    short8 Ah[2], Al[2];
#pragma unroll
    for (int ksp = 0; ksp < 2; ++ksp) {
      Ah[ksp] = *(const short8*)(Ch + srow * 64 + ksp * 32 + qd * 8);
      Al[ksp] = *(const short8*)(Cl + srow * 64 + ksp * 32 + qd * 8);
    }
    float c0r[4];
#pragma unroll
    for (int r = 0; r < 4; ++r) c0r[r] = c0z[rowZ + w * 16 + qd * 4 + r];
#pragma unroll
    for (int lt = 0; lt < 2; ++lt) {
      floatx4 y = {0.f, 0.f, 0.f, 0.f};
      y = __builtin_amdgcn_mfma_f32_16x16x32_bf16(Ah[0], Bbh[lt][0], y, 0, 0, 0);
      y = __builtin_amdgcn_mfma_f32_16x16x32_bf16(Ah[1], Bbh[lt][1], y, 0, 0, 0);
      y = __builtin_amdgcn_mfma_f32_16x16x32_bf16(Ah[0], Bbl[lt][0], y, 0, 0, 0);
      y = __builtin_amdgcn_mfma_f32_16x16x32_bf16(Ah[1], Bbl[lt][1], y, 0, 0, 0);
      y = __builtin_amdgcn_mfma_f32_16x16x32_bf16(Al[0], Bbh[lt][0], y, 0, 0, 0);
      y = __builtin_amdgcn_mfma_f32_16x16x32_bf16(Al[1], Bbh[lt][1], y, 0, 0, 0);
      unsigned short er[4];
#pragma unroll
      for (int r = 0; r < 4; ++r) er[r] = f2bf(__expf(y[r] + c0r[r]));
      uint2 e2;
      e2.x = (unsigned)er[0] | ((unsigned)er[1] << 16);
      e2.y = (unsigned)er[2] | ((unsigned)er[3] << 16);
      *(uint2*)(&Es[p][(lt * 16 + n) * 72 + w * 16 + qd * 4]) = e2;
    }
    __syncthreads();
    // PV-phase: wave w owns d-tile w; B-frags straight from global (L2)
#pragma unroll
    for (int ksp = 0; ksp < 2; ++ksp) {
      size_t vo = (((size_t)(bh * 32 + st)) * 8 + w * 2 + ksp) * 512 + lane * 8;
      short8 Bvh = *(const short8*)(Vf + vo);
      short8 Bvl = *(const short8*)(VfL + vo);
#pragma unroll
      for (int lt = 0; lt < 2; ++lt) {
        short8 Ef = *(const short8*)(&Es[p][(lt * 16 + n) * 72 + ksp * 32 + qd * 8]);
        accv[lt] = __builtin_amdgcn_mfma_f32_16x16x32_bf16(Ef, Bvh, accv[lt], 0, 0, 0);
        accv[lt] = __builtin_amdgcn_mfma_f32_16x16x32_bf16(Ef, Bvl, accv[lt], 0, 0, 0);
      }
    }
  }
  // Store: lane holds D[l = lt*16 + qd*4 + r][d = w*16 + n]; out layout [b][d][h][l]
#pragma unroll
  for (int lt = 0; lt < 2; ++lt) {
    size_t base = ((size_t)((b * 64 + w * 16 + n) * 8 + h)) * 2048 + l0 + lt * 16 + qd * 4;
    float4 o4;
    o4.x = accv[lt][0]; o4.y = accv[lt][1]; o4.z = accv[lt][2]; o4.w = accv[lt][3];
    *(float4*)(out + base) = o4;
  }
}

extern "C" void kernel_launch(void* const* d_in, const int* in_sizes, int n_in,
                              void* d_out, int out_size, void* d_ws, size_t ws_size,
                              hipStream_t stream) {
  const float* q = (const float*)d_in[0];
  const float* k = (const float*)d_in[1];
  const float* v = (const float*)d_in[2];
  float* out = (float*)d_out;
  float* ws = (float*)d_ws;
  float* c0s = ws + F_C0S;
  float* c0z = ws + F_C0Z;
  float* X2  = ws + F_X;
  unsigned short* ubase = (unsigned short*)(ws + F_END);
  unsigned short* Ch = ubase + U_CH;
  unsigned short* Cl = ubase + U_CL;
  unsigned short* Bf = ubase + U_BF;
  unsigned short* Tw = ubase + U_TW;
  unsigned short* Vf = (unsigned short*)X2;    // aliases X2 — written only after k2

  k0_basis<<<dim3(64), dim3(256), 0, stream>>>(Bf);
  k0b_tw<<<dim3(8), dim3(256), 0, stream>>>(Tw);
  k1_dft<<<dim3(512), dim3(256), 0, stream>>>(q, k, Tw, X2);
  k2_coef<<<dim3(4096), dim3(256), 0, stream>>>(X2, Ch, Cl, c0s);
  kv_frag<<<dim3(16, 32), dim3(256), 0, stream>>>(v, Vf);      // after k2 (alias)
  k3_z<<<dim3(512), dim3(256), 0, stream>>>(Ch, Cl, c0s, Bf, c0z);
  k4_out<<<dim3(16, 64), dim3(256), 0, stream>>>(Ch, Cl, c0z, Bf, Vf, out);
}

// Round 5
// 194.818 us; speedup vs baseline: 2.4943x; 1.0632x over previous
//
#include <hip/hip_runtime.h>
#include <math.h>

// B=2, H=8, L=2048, E=512, d=64
constexpr int CL = 2048;
constexpr int NROW = 32768;
constexpr float SCALE = 1.0f / 2048.0f;
constexpr float TWO_PI = 6.283185307179586f;

typedef short short8 __attribute__((ext_vector_type(8)));
typedef float floatx4 __attribute__((ext_vector_type(4)));

__device__ inline unsigned short f2bf(float f) {
  union { float f; unsigned u; } c; c.f = f;
  unsigned u = c.u + 0x7FFF + ((c.u >> 16) & 1);
  return (unsigned short)(u >> 16);
}
__device__ inline float bf2f(unsigned short h) {
  union { unsigned u; float f; } c; c.u = ((unsigned)h) << 16;
  return c.f;
}
// XOR swizzle for [rows][64 ushort] LDS tiles: 16B group g at row r -> g^(r&7).
__device__ inline int sw(int r, int o) {
  return r * 64 + ((((o >> 3) ^ r) & 7) << 3) + (o & 7);
}

// ---------------- workspace ----------------
// floats:  c0s[NROW] | c0z[NROW]
// ushorts: Ch[NROW*64] | Cl[NROW*64] | Bf[2*131072] | Tw[8192] | Vf[2*2097152]
constexpr size_t F_C0S = 0;
constexpr size_t F_C0Z = F_C0S + NROW;
constexpr size_t F_END = F_C0Z + NROW;
constexpr size_t U_CH  = 0;
constexpr size_t U_CL  = U_CH + (size_t)NROW * 64;
constexpr size_t U_BF  = U_CL + (size_t)NROW * 64;
constexpr size_t U_TW  = U_BF + (size_t)2 * 131072;
constexpr size_t U_VF  = U_TW + 8192;
constexpr size_t BF_SPLIT = 131072;
constexpr size_t VF_PLANE = 2097152;

// ---------------------------------------------------------------- k0: tables
// basis frags Bf + DFT twiddle frags Tw in one launch.
__global__ void k0_tabs(unsigned short* __restrict__ Bf, unsigned short* __restrict__ Tw) {
  int gid = blockIdx.x * 256 + threadIdx.x;
  if (gid < 16384) {
    int lt = gid >> 7, rem = gid & 127, ks = rem >> 6, lane = rem & 63;
    int q = lane >> 4, n = lane & 15;
    int t = lt * 16 + n;
    size_t base = ((size_t)((lt * 2 + ks) * 64 + lane)) * 8;
    for (int j = 0; j < 8; ++j) {
      int kr = ks * 32 + q * 8 + j;
      int freq = (kr < 32) ? (kr + 1) : (kr - 31);
      int ph = (freq * t) & (CL - 1);
      float ang = (float)ph * (TWO_PI / (float)CL);
      float val = (kr < 32) ? cosf(ang) : sinf(ang);
      unsigned short hi = f2bf(val);
      Bf[base + j] = hi;
      Bf[BF_SPLIT + base + j] = f2bf(val - bf2f(hi));
    }
  } else if (gid < 16384 + 2048) {
    int g = gid - 16384;
    int j = g & 7, lane = (g >> 3) & 63, ksp = (g >> 9) & 1, ct = g >> 10;
    int f = ct * 16 + (lane & 15);
    int c = ksp * 32 + ((lane >> 4) & 3) * 8 + j;
    float ang = (float)((f * c) & 63) * (TWO_PI / 64.0f);
    float re = cosf(ang), im = -sinf(ang);
    unsigned short rh = f2bf(re), ih = f2bf(im);
    Tw[g]        = rh;
    Tw[2048 + g] = f2bf(re - bf2f(rh));
    Tw[4096 + g] = ih;
    Tw[6144 + g] = f2bf(im - bf2f(ih));
  }
}

// ---------------------------------------------------------------- k1: fused DFT+coef
// Block = 8 s x 8 h of one b (64 rows, 4 waves x 16). Row lr = w*16+idx:
// s = s0 + 2w + (idx>>3), h = idx&7. Head-mean is in-wave (shfl) - X never stored.
__launch_bounds__(256)
__global__ void k1_coef(const float* __restrict__ q, const float* __restrict__ kin,
                        const unsigned short* __restrict__ Tw,
                        unsigned short* __restrict__ Ch, unsigned short* __restrict__ Cl,
                        float* __restrict__ c0s) {
  int tid = threadIdx.x;
  int w = tid >> 6, lane = tid & 63, qd = lane >> 4, n = lane & 15;
  int blk = blockIdx.x;                   // [0,512)
  int b = blk >> 8, s0 = (blk & 255) * 8;
  int sA = s0 + w * 2 + (n >> 3), hA = n & 7;
  const float* qp = q + ((size_t)(b * 2048 + sA)) * 512 + hA * 64 + qd * 8;
  const float* kp = kin + ((size_t)(b * 2048 + sA)) * 512 + hA * 64 + qd * 8;
  float qv[16], kv[16];
#pragma unroll
  for (int ksp = 0; ksp < 2; ++ksp) {
    float4 a0 = *(const float4*)(qp + ksp * 32);
    float4 a1 = *(const float4*)(qp + ksp * 32 + 4);
    float4 b0 = *(const float4*)(kp + ksp * 32);
    float4 b1 = *(const float4*)(kp + ksp * 32 + 4);
    qv[ksp*8+0]=a0.x; qv[ksp*8+1]=a0.y; qv[ksp*8+2]=a0.z; qv[ksp*8+3]=a0.w;
    qv[ksp*8+4]=a1.x; qv[ksp*8+5]=a1.y; qv[ksp*8+6]=a1.z; qv[ksp*8+7]=a1.w;
    kv[ksp*8+0]=b0.x; kv[ksp*8+1]=b0.y; kv[ksp*8+2]=b0.z; kv[ksp*8+3]=b0.w;
    kv[ksp*8+4]=b1.x; kv[ksp*8+5]=b1.y; kv[ksp*8+6]=b1.z; kv[ksp*8+7]=b1.w;
  }
  // Nyquist (f=32 of 64-pt DFT): alternating sum; parity of c = j&1.
  float aq = 0.0f, ak = 0.0f;
#pragma unroll
  for (int i = 0; i < 16; ++i) {
    float sg = (i & 1) ? -1.0f : 1.0f;
    aq += sg * qv[i]; ak += sg * kv[i];
  }
  aq += __shfl_xor(aq, 16); aq += __shfl_xor(aq, 32);
  ak += __shfl_xor(ak, 16); ak += __shfl_xor(ak, 32);
  // bf16 splits of A operands
  short8 Aqh[2], Aql[2], Akh[2], Akl[2];
#pragma unroll
  for (int ksp = 0; ksp < 2; ++ksp) {
#pragma unroll
    for (int j = 0; j < 8; ++j) {
      unsigned short hq = f2bf(qv[ksp*8+j]);
      Aqh[ksp][j] = (short)hq; Aql[ksp][j] = (short)f2bf(qv[ksp*8+j] - bf2f(hq));
      unsigned short hk = f2bf(kv[ksp*8+j]);
      Akh[ksp][j] = (short)hk; Akl[ksp][j] = (short)f2bf(kv[ksp*8+j] - bf2f(hk));
    }
  }
  float lmr[4] = {0,0,0,0};
  float c0v[4] = {0,0,0,0};
  int hC = (qd * 4) & 7;                 // rows qd*4+r: h = (qd*4+r)&7 = qd*4&7 + r
  int sC = s0 + w * 2 + (qd >> 1);
#pragma unroll
  for (int ct = 0; ct < 2; ++ct) {
    short8 Brh[2], Brl[2], Bih[2], Bil[2];
#pragma unroll
    for (int ksp = 0; ksp < 2; ++ksp) {
      size_t off = (size_t)ct * 1024 + ksp * 512 + lane * 8;
      Brh[ksp] = *(const short8*)(Tw + off);
      Brl[ksp] = *(const short8*)(Tw + 2048 + off);
      Bih[ksp] = *(const short8*)(Tw + 4096 + off);
      Bil[ksp] = *(const short8*)(Tw + 6144 + off);
    }
    floatx4 qre = {0,0,0,0}, qim = {0,0,0,0}, kre = {0,0,0,0}, kim = {0,0,0,0};
#pragma unroll
    for (int ksp = 0; ksp < 2; ++ksp) {
      qre = __builtin_amdgcn_mfma_f32_16x16x32_bf16(Aqh[ksp], Brh[ksp], qre, 0,0,0);
      qre = __builtin_amdgcn_mfma_f32_16x16x32_bf16(Aqh[ksp], Brl[ksp], qre, 0,0,0);
      qre = __builtin_amdgcn_mfma_f32_16x16x32_bf16(Aql[ksp], Brh[ksp], qre, 0,0,0);
      qim = __builtin_amdgcn_mfma_f32_16x16x32_bf16(Aqh[ksp], Bih[ksp], qim, 0,0,0);
      qim = __builtin_amdgcn_mfma_f32_16x16x32_bf16(Aqh[ksp], Bil[ksp], qim, 0,0,0);
      qim = __builtin_amdgcn_mfma_f32_16x16x32_bf16(Aql[ksp], Bih[ksp], qim, 0,0,0);
      kre = __builtin_amdgcn_mfma_f32_16x16x32_bf16(Akh[ksp], Brh[ksp], kre, 0,0,0);
      kre = __builtin_amdgcn_mfma_f32_16x16x32_bf16(Akh[ksp], Brl[ksp], kre, 0,0,0);
      kre = __builtin_amdgcn_mfma_f32_16x16x32_bf16(Akl[ksp], Brh[ksp], kre, 0,0,0);
      kim = __builtin_amdgcn_mfma_f32_16x16x32_bf16(Akh[ksp], Bih[ksp], kim, 0,0,0);
      kim = __builtin_amdgcn_mfma_f32_16x16x32_bf16(Akh[ksp], Bil[ksp], kim, 0,0,0);
      kim = __builtin_amdgcn_mfma_f32_16x16x32_bf16(Akl[ksp], Bih[ksp], kim, 0,0,0);
    }
    float xre[4], xim[4], tre = 0, tim = 0;
#pragma unroll
    for (int r = 0; r < 4; ++r) {
      xre[r] = qre[r] * kre[r] + qim[r] * kim[r];
      xim[r] = qim[r] * kre[r] - qre[r] * kim[r];
      tre += xre[r]; tim += xim[r];
    }
    tre += __shfl_xor(tre, 16);          // qd0+qd1 (s-group 0), qd2+qd3 (s-group 1)
    tim += __shfl_xor(tim, 16);
    float mre = tre * 0.125f, mim = tim * 0.125f;
#pragma unroll
    for (int r = 0; r < 4; ++r) {
      float yre = xre[r] - mre, yim = xim[r] - mim;
      if (ct == 0 && n == 0) {
        c0v[r] = yre * SCALE;
      } else {
        int f = ct * 16 + n;
        float a = 2.0f * yre * SCALE, bb = -2.0f * yim * SCALE;
        size_t rowid = (size_t)((b * 8 + hC + r) * 2048 + sC);
        unsigned short ah = f2bf(a);
        Ch[rowid * 64 + f - 1] = ah;
        Cl[rowid * 64 + f - 1] = f2bf(a - bf2f(ah));
        unsigned short bh2 = f2bf(bb);
        Ch[rowid * 64 + 32 + f - 1] = bh2;
        Cl[rowid * 64 + 32 + f - 1] = f2bf(bb - bf2f(bh2));
        lmr[r] += fabsf(a) + fabsf(bb);
      }
    }
  }
  // Nyquist coef (f=32 -> j=31); X32 real, head-mean over n-octet.
  float X32 = aq * ak;
  float m32 = X32;
  m32 += __shfl_xor(m32, 1); m32 += __shfl_xor(m32, 2); m32 += __shfl_xor(m32, 4);
  float A32 = 2.0f * (X32 - m32 * 0.125f) * SCALE;
  if (qd == 0) {
    size_t rowid = (size_t)((b * 8 + (n & 7)) * 2048 + s0 + w * 2 + (n >> 3));
    unsigned short ah = f2bf(A32);
    Ch[rowid * 64 + 31] = ah;
    Cl[rowid * 64 + 31] = f2bf(A32 - bf2f(ah));
    Ch[rowid * 64 + 63] = 0;
    Cl[rowid * 64 + 63] = 0;
  }
  float absA32 = fabsf(A32);
#pragma unroll
  for (int r = 0; r < 4; ++r) {
    lmr[r] += __shfl_xor(lmr[r], 1);
    lmr[r] += __shfl_xor(lmr[r], 2);
    lmr[r] += __shfl_xor(lmr[r], 4);
    lmr[r] += __shfl_xor(lmr[r], 8);
  }
  int qb = lane & 48;
#pragma unroll
  for (int r = 0; r < 4; ++r) {
    float a32r = __shfl(absA32, qb + (qb >> 2) + r);   // A32 of row qd*4+r
    if (n == 0) {
      float M = fabsf(c0v[r]) + lmr[r] + a32r;
      size_t rowid = (size_t)((b * 8 + hC + r) * 2048 + sC);
      c0s[rowid] = c0v[r] - M;
    }
  }
}

// ---------------------------------------------------------------- kv: V frags (hi/lo)
__global__ void kv_frag(const float* __restrict__ values, unsigned short* __restrict__ Vf) {
  __shared__ float Vt[64 * 65];
  int tid = threadIdx.x;
  int bh = blockIdx.x, st = blockIdx.y;
  int b = bh >> 3, h = bh & 7;
  {
    int sl = tid >> 2, dq = (tid & 3) * 16;
    const float4* src = (const float4*)(values + ((size_t)(b * 2048 + st * 64 + sl)) * 512 + h * 64 + dq);
#pragma unroll
    for (int m = 0; m < 4; ++m) {
      float4 t = src[m];
      int base = sl * 65 + dq + m * 4;
      Vt[base] = t.x; Vt[base + 1] = t.y; Vt[base + 2] = t.z; Vt[base + 3] = t.w;
    }
  }
  __syncthreads();
#pragma unroll
  for (int iter = 0; iter < 2; ++iter) {
    int it = iter * 256 + tid;
    int lane = it & 63, ksp = (it >> 6) & 1, dt = it >> 7;
    int qd = lane >> 4, n = lane & 15;
    int d = dt * 16 + n;
    short8 hi, lo;
#pragma unroll
    for (int j = 0; j < 8; ++j) {
      float f = Vt[(ksp * 32 + qd * 8 + j) * 65 + d];
      unsigned short h2 = f2bf(f);
      hi[j] = (short)h2; lo[j] = (short)f2bf(f - bf2f(h2));
    }
    size_t off = (((size_t)(bh * 32 + st)) * 8 + dt * 2 + ksp) * 512 + lane * 8;
    *(short8*)(Vf + off) = hi;
    *(short8*)(Vf + VF_PLANE + off) = lo;
  }
}

// ---------------------------------------------------------------- k3: c0z = c0 - log(Z)
__launch_bounds__(256)
__global__ void k3_z(const unsigned short* __restrict__ Ch, const unsigned short* __restrict__ Cl,
                     const float* __restrict__ c0s, const unsigned short* __restrict__ Bf,
                     float* __restrict__ c0z) {
  __shared__ float Zl[64];
  int tid = threadIdx.x;
  int w = tid >> 6, lane = tid & 63, q = lane >> 4, n = lane & 15;
  int rowbase = blockIdx.x * 64;
  short8 Ah[4][2], Al[4][2];
#pragma unroll
  for (int c = 0; c < 4; ++c)
#pragma unroll
    for (int ksp = 0; ksp < 2; ++ksp) {
      size_t srow = (size_t)(rowbase + c * 16 + n);
      Ah[c][ksp] = *(const short8*)(Ch + srow * 64 + ksp * 32 + q * 8);
      Al[c][ksp] = *(const short8*)(Cl + srow * 64 + ksp * 32 + q * 8);
    }
  float c0r[4][4], zacc[4][4];
#pragma unroll
  for (int c = 0; c < 4; ++c)
#pragma unroll
    for (int r = 0; r < 4; ++r) {
      c0r[c][r] = c0s[rowbase + c * 16 + q * 4 + r];
      zacc[c][r] = 0.0f;
    }
  if (tid < 64) Zl[tid] = 0.0f;
  const unsigned short* BfL = Bf + BF_SPLIT;
  for (int lt = w; lt < 128; lt += 4) {
    size_t b0 = ((size_t)(lt * 2 + 0) * 64 + lane) * 8;
    size_t b1 = ((size_t)(lt * 2 + 1) * 64 + lane) * 8;
    short8 Bh0 = *(const short8*)(Bf + b0);
    short8 Bh1 = *(const short8*)(Bf + b1);
    short8 Bl0 = *(const short8*)(BfL + b0);
    short8 Bl1 = *(const short8*)(BfL + b1);
#pragma unroll
    for (int c = 0; c < 4; ++c) {
      floatx4 y = {0.f, 0.f, 0.f, 0.f};
      y = __builtin_amdgcn_mfma_f32_16x16x32_bf16(Ah[c][0], Bh0, y, 0, 0, 0);
      y = __builtin_amdgcn_mfma_f32_16x16x32_bf16(Ah[c][1], Bh1, y, 0, 0, 0);
      y = __builtin_amdgcn_mfma_f32_16x16x32_bf16(Ah[c][0], Bl0, y, 0, 0, 0);
      y = __builtin_amdgcn_mfma_f32_16x16x32_bf16(Ah[c][1], Bl1, y, 0, 0, 0);
      y = __builtin_amdgcn_mfma_f32_16x16x32_bf16(Al[c][0], Bh0, y, 0, 0, 0);
      y = __builtin_amdgcn_mfma_f32_16x16x32_bf16(Al[c][1], Bh1, y, 0, 0, 0);
#pragma unroll
      for (int r = 0; r < 4; ++r) zacc[c][r] += __expf(y[r] + c0r[c][r]);
    }
  }
  __syncthreads();
#pragma unroll
  for (int c = 0; c < 4; ++c)
#pragma unroll
    for (int r = 0; r < 4; ++r) {
#pragma unroll
      for (int m = 1; m < 16; m <<= 1) zacc[c][r] += __shfl_xor(zacc[c][r], m, 16);
      if (n == 0) atomicAdd(&Zl[c * 16 + q * 4 + r], zacc[c][r]);
    }
  __syncthreads();
  if (tid < 64) c0z[rowbase + tid] = c0s[rowbase + tid] - __logf(Zl[tid]);
}

// ---------------------------------------------------------------- k4: output (pipelined)
#define K4_LOADST(st_, slot_)                                                        \
  do {                                                                               \
    int rz_ = bh * 2048 + (st_) * 64;                                                \
    size_t srow_ = (size_t)(rz_ + w * 16 + n);                                       \
    Ahs[slot_][0] = *(const short8*)(Ch + srow_ * 64 + qd * 8);                      \
    Ahs[slot_][1] = *(const short8*)(Ch + srow_ * 64 + 32 + qd * 8);                 \
    Als[slot_][0] = *(const short8*)(Cl + srow_ * 64 + qd * 8);                      \
    Als[slot_][1] = *(const short8*)(Cl + srow_ * 64 + 32 + qd * 8);                 \
    c0rs[slot_] = *(const float4*)(c0z + rz_ + w * 16 + qd * 4);                     \
    size_t vo_ = (((size_t)(bh * 32 + (st_))) * 8 + w * 2) * 512 + lane * 8;         \
    Vhs[slot_][0] = *(const short8*)(Vf + vo_);                                      \
    Vhs[slot_][1] = *(const short8*)(Vf + vo_ + 512);                                \
    Vls[slot_][0] = *(const short8*)(VfL + vo_);                                     \
    Vls[slot_][1] = *(const short8*)(VfL + vo_ + 512);                               \
  } while (0)

#define K4_STEP(st_, slot_, last_)                                                   \
  do {                                                                               \
    const int p_ = (st_) & 1;                                                        \
    floatx4 y0 = {0,0,0,0}, y1 = {0,0,0,0};                                          \
    y0 = __builtin_amdgcn_mfma_f32_16x16x32_bf16(Ahs[slot_][0], Bbh[0][0], y0,0,0,0);\
    y0 = __builtin_amdgcn_mfma_f32_16x16x32_bf16(Ahs[slot_][1], Bbh[0][1], y0,0,0,0);\
    y0 = __builtin_amdgcn_mfma_f32_16x16x32_bf16(Ahs[slot_][0], Bbl[0][0], y0,0,0,0);\
    y0 = __builtin_amdgcn_mfma_f32_16x16x32_bf16(Ahs[slot_][1], Bbl[0][1], y0,0,0,0);\
    y0 = __builtin_amdgcn_mfma_f32_16x16x32_bf16(Als[slot_][0], Bbh[0][0], y0,0,0,0);\
    y0 = __builtin_amdgcn_mfma_f32_16x16x32_bf16(Als[slot_][1], Bbh[0][1], y0,0,0,0);\
    y1 = __builtin_amdgcn_mfma_f32_16x16x32_bf16(Ahs[slot_][0], Bbh[1][0], y1,0,0,0);\
    y1 = __builtin_amdgcn_mfma_f32_16x16x32_bf16(Ahs[slot_][1], Bbh[1][1], y1,0,0,0);\
    y1 = __builtin_amdgcn_mfma_f32_16x16x32_bf16(Ahs[slot_][0], Bbl[1][0], y1,0,0,0);\
    y1 = __builtin_amdgcn_mfma_f32_16x16x32_bf16(Ahs[slot_][1], Bbl[1][1], y1,0,0,0);\
    y1 = __builtin_amdgcn_mfma_f32_16x16x32_bf16(Als[slot_][0], Bbh[1][0], y1,0,0,0);\
    y1 = __builtin_amdgcn_mfma_f32_16x16x32_bf16(Als[slot_][1], Bbh[1][1], y1,0,0,0);\
    if (!(last_)) { K4_LOADST((st_) + 1, 1 - (slot_)); }                             \
    float4 cc_ = c0rs[slot_];                                                        \
    unsigned short e0_[4], e1_[4];                                                   \
    e0_[0] = f2bf(__expf(y0[0] + cc_.x)); e0_[1] = f2bf(__expf(y0[1] + cc_.y));      \
    e0_[2] = f2bf(__expf(y0[2] + cc_.z)); e0_[3] = f2bf(__expf(y0[3] + cc_.w));      \
    e1_[0] = f2bf(__expf(y1[0] + cc_.x)); e1_[1] = f2bf(__expf(y1[1] + cc_.y));      \
    e1_[2] = f2bf(__expf(y1[2] + cc_.z)); e1_[3] = f2bf(__expf(y1[3] + cc_.w));      \
    uint2 p0_, p1_;                                                                  \
    p0_.x = (unsigned)e0_[0] | ((unsigned)e0_[1] << 16);                             \
    p0_.y = (unsigned)e0_[2] | ((unsigned)e0_[3] << 16);                             \
    p1_.x = (unsigned)e1_[0] | ((unsigned)e1_[1] << 16);                             \
    p1_.y = (unsigned)e1_[2] | ((unsigned)e1_[3] << 16);                             \
    *(uint2*)(&Es[p_][sw(n, w * 16 + qd * 4)]) = p0_;                                \
    *(uint2*)(&Es[p_][sw(16 + n, w * 16 + qd * 4)]) = p1_;                           \
    __syncthreads();                                                                 \
    _Pragma("unroll")                                                                \
    for (int ksp_ = 0; ksp_ < 2; ++ksp_) {                                           \
      short8 E0_ = *(const short8*)(&Es[p_][sw(n, ksp_ * 32 + qd * 8)]);             \
      short8 E1_ = *(const short8*)(&Es[p_][sw(16 + n, ksp_ * 32 + qd * 8)]);        \
      accv[0] = __builtin_amdgcn_mfma_f32_16x16x32_bf16(E0_, Vhs[slot_][ksp_], accv[0],0,0,0);\
      accv[0] = __builtin_amdgcn_mfma_f32_16x16x32_bf16(E0_, Vls[slot_][ksp_], accv[0],0,0,0);\
      accv[1] = __builtin_amdgcn_mfma_f32_16x16x32_bf16(E1_, Vhs[slot_][ksp_], accv[1],0,0,0);\
      accv[1] = __builtin_amdgcn_mfma_f32_16x16x32_bf16(E1_, Vls[slot_][ksp_], accv[1],0,0,0);\
    }                                                                                \
  } while (0)

__launch_bounds__(256, 4)
__global__ void k4_out(const unsigned short* __restrict__ Ch, const unsigned short* __restrict__ Cl,
                       const float* __restrict__ c0z, const unsigned short* __restrict__ Bf,
                       const unsigned short* __restrict__ Vf, float* __restrict__ out) {
  __shared__ unsigned short Es[2][32 * 64];
  int tid = threadIdx.x;
  int w = tid >> 6, lane = tid & 63, qd = lane >> 4, n = lane & 15;
  int bh = blockIdx.x, b = bh >> 3, h = bh & 7;
  int l0 = blockIdx.y * 32, lt0 = blockIdx.y * 2;
  const unsigned short* BfL = Bf + BF_SPLIT;
  const unsigned short* VfL = Vf + VF_PLANE;
  short8 Bbh[2][2], Bbl[2][2];
#pragma unroll
  for (int lt = 0; lt < 2; ++lt)
#pragma unroll
    for (int ksp = 0; ksp < 2; ++ksp) {
      size_t bo = ((size_t)((lt0 + lt) * 2 + ksp) * 64 + lane) * 8;
      Bbh[lt][ksp] = *(const short8*)(Bf + bo);
      Bbl[lt][ksp] = *(const short8*)(BfL + bo);
    }
  floatx4 accv[2];
  accv[0] = (floatx4){0.f, 0.f, 0.f, 0.f};
  accv[1] = (floatx4){0.f, 0.f, 0.f, 0.f};
  short8 Ahs[2][2], Als[2][2], Vhs[2][2], Vls[2][2];
  float4 c0rs[2];
  K4_LOADST(0, 0);
  for (int st2 = 0; st2 < 16; ++st2) {
    K4_STEP(2 * st2, 0, false);
    K4_STEP(2 * st2 + 1, 1, st2 == 15);
  }
#pragma unroll
  for (int lt = 0; lt < 2; ++lt) {
    size_t base = ((size_t)((b * 64 + w * 16 + n) * 8 + h)) * 2048 + l0 + lt * 16 + qd * 4;
    float4 o4;
    o4.x = accv[lt][0]; o4.y = accv[lt][1]; o4.z = accv[lt][2]; o4.w = accv[lt][3];
    *(float4*)(out + base) = o4;
  }
}

extern "C" void kernel_launch(void* const* d_in, const int* in_sizes, int n_in,
                              void* d_out, int out_size, void* d_ws, size_t ws_size,
                              hipStream_t stream) {
  const float* q = (const float*)d_in[0];
  const float* k = (const float*)d_in[1];
  const float* v = (const float*)d_in[2];
  float* out = (float*)d_out;
  float* ws = (float*)d_ws;
  float* c0s = ws + F_C0S;
  float* c0z = ws + F_C0Z;
  unsigned short* ubase = (unsigned short*)(ws + F_END);
  unsigned short* Ch = ubase + U_CH;
  unsigned short* Cl = ubase + U_CL;
  unsigned short* Bf = ubase + U_BF;
  unsigned short* Tw = ubase + U_TW;
  unsigned short* Vf = ubase + U_VF;

  k0_tabs<<<dim3(72), dim3(256), 0, stream>>>(Bf, Tw);
  kv_frag<<<dim3(16, 32), dim3(256), 0, stream>>>(v, Vf);
  k1_coef<<<dim3(512), dim3(256), 0, stream>>>(q, k, Tw, Ch, Cl, c0s);
  k3_z<<<dim3(512), dim3(256), 0, stream>>>(Ch, Cl, c0s, Bf, c0z);
  k4_out<<<dim3(16, 64), dim3(256), 0, stream>>>(Ch, Cl, c0z, Bf, Vf, out);
}